// Round 1
// 1432.187 us; speedup vs baseline: 1.0066x; 1.0066x over previous
//
#include <hip/hip_runtime.h>
#include <cfloat>

#define N_NODES 50000
#define N_EDGES 600000
#define DIM 128
#define N_GRAPHS 256
#define HIDDEN 256
#define OUT_DIM 16
#define MAX_DEG 10
#define MAX_TBL 1600

__device__ __forceinline__ float4 relu4(float4 v) {
  return make_float4(fmaxf(v.x, 0.f), fmaxf(v.y, 0.f), fmaxf(v.z, 0.f), fmaxf(v.w, 0.f));
}
__device__ __forceinline__ void add4(float4& a, const float4 v) {
  a.x += v.x; a.y += v.y; a.z += v.z; a.w += v.w;
}
__device__ __forceinline__ void fma4(float4& a, float m, const float4 v) {
  a.x = fmaf(m, v.x, a.x); a.y = fmaf(m, v.y, a.y);
  a.z = fmaf(m, v.z, a.z); a.w = fmaf(m, v.w, a.w);
}
__device__ __forceinline__ void max4(float4& a, const float4 v) {
  a.x = fmaxf(a.x, v.x); a.y = fmaxf(a.y, v.y);
  a.z = fmaxf(a.z, v.z); a.w = fmaxf(a.w, v.w);
}

// ---------------- CSR build ----------------
__global__ void k_deg_count(const int* __restrict__ col, int* __restrict__ deg) {
  int e = blockIdx.x * blockDim.x + threadIdx.x;
  if (e < N_EDGES) atomicAdd(&deg[col[e]], 1);
}

// Fused: exclusive scan (rowptr/cursor) + degree histogram (ballot) + bucket
// table + bucket cursors + graph bounds. Single block, 1024 threads.
__global__ void k_setup(const int* __restrict__ deg, const int* __restrict__ batch,
                        int* __restrict__ rowptr, int* __restrict__ cursor,
                        int* __restrict__ bcur, int* __restrict__ tbl_d,
                        int* __restrict__ tbl_base, int* __restrict__ tbl_cnt,
                        int* __restrict__ gstart) {
  __shared__ int tsum[1024];
  __shared__ int hist[MAX_DEG + 1];
  __shared__ int boff[MAX_DEG + 1];
  __shared__ int tblStart[MAX_DEG + 2];
  const int CH = (N_NODES + 1023) / 1024;  // 49
  int t = threadIdx.x;
  if (t <= MAX_DEG) hist[t] = 0;
  __syncthreads();
  // histogram via wave ballot (11 shared atomics per 64 nodes, no LDS-atomic storm)
  for (int base2 = 0; base2 < N_NODES; base2 += 1024) {
    int i = base2 + t;
    int d = (i < N_NODES) ? min(deg[i], MAX_DEG) : -1;
#pragma unroll
    for (int dd = 0; dd <= MAX_DEG; ++dd) {
      unsigned long long m = __ballot(d == dd);
      if ((t & 63) == 0 && m) atomicAdd(&hist[dd], (int)__popcll(m));
    }
  }
  // per-thread chunk sums for the scan
  int lo = t * CH, hi = min(lo + CH, N_NODES);
  int s = 0;
  for (int i = lo; i < hi; ++i) s += deg[i];
  tsum[t] = s;
  __syncthreads();
  for (int off = 1; off < 1024; off <<= 1) {
    int v = (t >= off) ? tsum[t - off] : 0;
    __syncthreads();
    tsum[t] += v;
    __syncthreads();
  }
  int pre = (t == 0) ? 0 : tsum[t - 1];
  for (int i = lo; i < hi; ++i) { rowptr[i] = pre; cursor[i] = pre; pre += deg[i]; }
  if (t == 1023) rowptr[N_NODES] = tsum[1023];
  // bucket offsets + table starts (serial, 11 iters)
  if (t == 0) {
    int off = 0, nb = 0;
    for (int d = 0; d <= MAX_DEG; ++d) {
      boff[d] = off; bcur[d] = off; off += hist[d];
      tblStart[d] = nb; nb += (hist[d] + 31) / 32;
    }
    tblStart[MAX_DEG + 1] = nb;
  }
  __syncthreads();
  int totalb = tblStart[MAX_DEG + 1];
  for (int d = 0; d <= MAX_DEG; ++d) {
    int nblk = (hist[d] + 31) / 32;
    int st = tblStart[d];
    for (int idx = t; idx < nblk; idx += 1024) {
      tbl_d[st + idx] = d;
      tbl_base[st + idx] = boff[d] + idx * 32;
      tbl_cnt[st + idx] = min(32, hist[d] - idx * 32);
    }
  }
  for (int idx = totalb + t; idx < MAX_TBL; idx += 1024) tbl_d[idx] = -1;
  // graph bounds (binary search on sorted batch)
  for (int g = t; g <= N_GRAPHS; g += 1024) {
    int lo2 = 0, hi2 = N_NODES;
    while (lo2 < hi2) {
      int mid = (lo2 + hi2) >> 1;
      if (batch[mid] < g) lo2 = mid + 1; else hi2 = mid;
    }
    gstart[g] = lo2;
  }
}

// Fused CSR edge scatter + degree-bucket node scatter (one dispatch, two roles)
__global__ void k_scatter_fused(const int* __restrict__ row, const int* __restrict__ col,
                                int* __restrict__ cursor, int* __restrict__ src,
                                const int* __restrict__ deg, int* __restrict__ bcur,
                                int* __restrict__ nlist) {
  const int NB = (N_NODES + 255) / 256;
  int b = blockIdx.x;
  if (b < NB) {
    __shared__ int lh[MAX_DEG + 1];
    __shared__ int gbase[MAX_DEG + 1];
    int t = threadIdx.x;
    if (t <= MAX_DEG) lh[t] = 0;
    __syncthreads();
    int i = b * 256 + t;
    int bk = 0, r = 0;
    if (i < N_NODES) { bk = min(deg[i], MAX_DEG); r = atomicAdd(&lh[bk], 1); }
    __syncthreads();
    if (t <= MAX_DEG) gbase[t] = lh[t] ? atomicAdd(&bcur[t], lh[t]) : 0;
    __syncthreads();
    if (i < N_NODES) nlist[gbase[bk] + r] = i;
  } else {
    int e = (b - NB) * 256 + threadIdx.x;
    if (e < N_EDGES) {
      int p = atomicAdd(&cursor[col[e]], 1);
      src[p] = row[e];
    }
  }
}

// ---------------- Fused MFConv ----------------
// Inputs are pre-activated (pass 0: raw x; pass 1: relu'd tmpNr written by pass 0).
// RELU_STORE=true writes relu(acc) (pass-0 output feeds only relu'd consumers).
// xs dropped from LDS: root-term rows read from global (L1 broadcast) ->
// LDS 32.8->16.5 KB (occupancy 2x), LDS broadcast instrs halved.
template <bool RELU_STORE>
__global__ __launch_bounds__(128) void kMF_fused(
    const float* __restrict__ x, const float* __restrict__ W_lin,
    const float* __restrict__ b_lin, const float* __restrict__ W_root,
    const int* __restrict__ rowptr, const int* __restrict__ src,
    const int* __restrict__ tbl_d, const int* __restrict__ tbl_base,
    const int* __restrict__ tbl_cnt, const int* __restrict__ nlist,
    float* __restrict__ out) {
  int b = blockIdx.x;
  int d = tbl_d[b];
  if (d < 0) return;
  int base = tbl_base[b], cnt = tbl_cnt[b];
  __shared__ float hs[32][DIM];
  __shared__ int nid[32];
  int j = threadIdx.x;
  if (j < 32) nid[j] = nlist[base + min(j, cnt - 1)];
  __syncthreads();
  int q = j >> 5, l = j & 31;
  // gather phase: 32-lane group q handles nodes i = q, q+4, ... (8 nodes)
  for (int i = q; i < 32; i += 4) {
    int node = nid[i];
    int s = rowptr[node], e = rowptr[node + 1];
    float4 a = make_float4(0.f, 0.f, 0.f, 0.f);
    for (int p = s; p < e; p += 4) {
      int e1 = e - 1;
      int i0 = src[p], i1 = src[min(p + 1, e1)];
      int i2 = src[min(p + 2, e1)], i3 = src[min(p + 3, e1)];
      float4 v0 = ((const float4*)(x + (size_t)i0 * DIM))[l];
      float4 v1 = ((const float4*)(x + (size_t)i1 * DIM))[l];
      float4 v2 = ((const float4*)(x + (size_t)i2 * DIM))[l];
      float4 v3 = ((const float4*)(x + (size_t)i3 * DIM))[l];
      add4(a, v0);
      fma4(a, (p + 1 < e) ? 1.f : 0.f, v1);
      fma4(a, (p + 2 < e) ? 1.f : 0.f, v2);
      fma4(a, (p + 3 < e) ? 1.f : 0.f, v3);
    }
    ((float4*)&hs[i][0])[l] = a;
  }
  __syncthreads();
  // matvec phase: thread j computes output column j for all 32 nodes
  int off[32];
#pragma unroll
  for (int i = 0; i < 32; ++i) off[i] = nid[i] * DIM;
  const float* Wl = W_lin + (size_t)d * DIM * DIM + j;
  const float* Wr = W_root + (size_t)d * DIM * DIM + j;
  float bl = b_lin[d * DIM + j];
  float acc[32];
#pragma unroll
  for (int i = 0; i < 32; ++i) acc[i] = bl;
  for (int k = 0; k < DIM; k += 4) {
    float wl0 = Wl[(k + 0) * DIM], wl1 = Wl[(k + 1) * DIM];
    float wl2 = Wl[(k + 2) * DIM], wl3 = Wl[(k + 3) * DIM];
    float wr0 = Wr[(k + 0) * DIM], wr1 = Wr[(k + 1) * DIM];
    float wr2 = Wr[(k + 2) * DIM], wr3 = Wr[(k + 3) * DIM];
#pragma unroll
    for (int i = 0; i < 32; ++i) {
      float4 hv = *(const float4*)&hs[i][k];              // LDS broadcast
      float4 xv = *(const float4*)(x + off[i] + k);       // global L1 broadcast
      acc[i] += hv.x * wl0 + hv.y * wl1 + hv.z * wl2 + hv.w * wl3 +
                xv.x * wr0 + xv.y * wr1 + xv.z * wr2 + xv.w * wr3;
    }
  }
  for (int i = 0; i < 32; ++i)
    if (i < cnt) {
      float v = acc[i];
      if (RELU_STORE) v = fmaxf(v, 0.f);
      out[(size_t)nid[i] * DIM + j] = v;
    }
}

// ---------------- EdgeConv GEMM: B = e@W_bot, C = e@(W_top - W_bot) ----------------
template <bool RELU>
__global__ __launch_bounds__(128) void kEG_gemm(
    const float* __restrict__ e, const float* __restrict__ W,
    float* __restrict__ Bm, float* __restrict__ Cm) {
  int base = blockIdx.x * 32;
  int j = threadIdx.x;
  int cnt = min(32, N_NODES - base);
  __shared__ float es[32][DIM];
#pragma unroll 4
  for (int i = 0; i < 32; ++i) {
    int r = base + min(i, cnt - 1);
    float v = e[(size_t)r * DIM + j];
    if (RELU) v = fmaxf(v, 0.f);
    es[i][j] = v;
  }
  __syncthreads();
  float accB[32], accC[32];
#pragma unroll
  for (int i = 0; i < 32; ++i) { accB[i] = 0.f; accC[i] = 0.f; }
  const float* Wt = W + j;              // rows [0,128)   = W_top
  const float* Wb = W + 128 * DIM + j;  // rows [128,256) = W_bot
  for (int k = 0; k < DIM; k += 4) {
    float wb0 = Wb[(k + 0) * DIM], wb1 = Wb[(k + 1) * DIM];
    float wb2 = Wb[(k + 2) * DIM], wb3 = Wb[(k + 3) * DIM];
    float wd0 = Wt[(k + 0) * DIM] - wb0, wd1 = Wt[(k + 1) * DIM] - wb1;
    float wd2 = Wt[(k + 2) * DIM] - wb2, wd3 = Wt[(k + 3) * DIM] - wb3;
#pragma unroll
    for (int i = 0; i < 32; ++i) {
      float4 ev = *(const float4*)&es[i][k];
      accB[i] += ev.x * wb0 + ev.y * wb1 + ev.z * wb2 + ev.w * wb3;
      accC[i] += ev.x * wd0 + ev.y * wd1 + ev.z * wd2 + ev.w * wd3;
    }
  }
  for (int i = 0; i < 32; ++i)
    if (i < cnt) {
      Bm[(size_t)(base + i) * DIM + j] = accB[i];
      Cm[(size_t)(base + i) * DIM + j] = accC[i];
    }
}

// out[i] = (deg==0) ? 0 : C[i] + b_edge + max_{incoming} B[src]  (unroll-8)
__global__ void kEA_aggr(const float* __restrict__ Bm, const float* __restrict__ Cm,
                         const float* __restrict__ b_edge, const int* __restrict__ deg,
                         const int* __restrict__ rowptr, const int* __restrict__ src,
                         float* __restrict__ out) {
  int node = blockIdx.x * 4 + (threadIdx.x >> 5);
  int l = threadIdx.x & 31;
  if (node >= N_NODES) return;
  float4* o = (float4*)(out + (size_t)node * DIM);
  if (deg[node] == 0) { o[l] = make_float4(0.f, 0.f, 0.f, 0.f); return; }
  int s = rowptr[node], e = rowptr[node + 1];
  const float4 c = ((const float4*)(Cm + (size_t)node * DIM))[l];
  const float4 be = ((const float4*)b_edge)[l];
  float4 m = make_float4(-FLT_MAX, -FLT_MAX, -FLT_MAX, -FLT_MAX);
  for (int p = s; p < e; p += 8) {  // max is idempotent: clamped dup loads are free
    int e1 = e - 1;
    int idx[8];
#pragma unroll
    for (int u = 0; u < 8; ++u) idx[u] = src[min(p + u, e1)];
#pragma unroll
    for (int u = 0; u < 8; ++u)
      max4(m, ((const float4*)(Bm + (size_t)idx[u] * DIM))[l]);
  }
  o[l] = make_float4(c.x + be.x + m.x, c.y + be.y + m.y,
                     c.z + be.z + m.z, c.w + be.w + m.w);
}

// h_final[i] = sum relu(x[src]) for readout  (unroll-8)
__global__ void kA_final(const float* __restrict__ x, const int* __restrict__ rowptr,
                         const int* __restrict__ src, float* __restrict__ h) {
  int node = blockIdx.x * 4 + (threadIdx.x >> 5);
  int l = threadIdx.x & 31;
  if (node >= N_NODES) return;
  int s = rowptr[node], e = rowptr[node + 1];
  float4 a = make_float4(0.f, 0.f, 0.f, 0.f);
  for (int p = s; p < e; p += 8) {
    int e1 = e - 1;
    int idx[8];
    float msk[8];
#pragma unroll
    for (int u = 0; u < 8; ++u) {
      idx[u] = src[min(p + u, e1)];
      msk[u] = (p + u < e) ? 1.f : 0.f;
    }
#pragma unroll
    for (int u = 0; u < 8; ++u) {
      float4 v = relu4(((const float4*)(x + (size_t)idx[u] * DIM))[l]);
      fma4(a, msk[u], v);
    }
  }
  ((float4*)(h + (size_t)node * DIM))[l] = a;
}

// ---------------- Readout ----------------
__global__ void k_pool(const float* __restrict__ hf, const float* __restrict__ embE,
                       const int* __restrict__ deg, const int* __restrict__ gstart,
                       float* __restrict__ gf) {
  int g = blockIdx.x;
  int j = threadIdx.x;  // 256
  int s = gstart[g], e = gstart[g + 1];
  float acc = 0.f;
  if (j < DIM) {
    for (int i = s; i < e; ++i) acc += hf[(size_t)i * DIM + j];
  } else {
    int jj = j - DIM;
    for (int i = s; i < e; ++i)
      acc += (float)deg[i] * fmaxf(embE[(size_t)i * DIM + jj], 0.f);
  }
  gf[g * 256 + j] = acc;
}

__global__ void k_mlp0(const float* __restrict__ gf, const float* __restrict__ W0,
                       const float* __restrict__ b0, float* __restrict__ o) {
  int g = blockIdx.x, j = threadIdx.x;  // 256
  __shared__ float gs[256];
  gs[j] = gf[g * 256 + j];
  __syncthreads();
  float acc = b0[j];
  for (int k = 0; k < 256; ++k) acc += gs[k] * W0[k * 256 + j];
  o[g * 256 + j] = fmaxf(acc, 0.f);
}

__global__ void k_mlp1(const float* __restrict__ m0, const float* __restrict__ W1,
                       const float* __restrict__ b1, float* __restrict__ out) {
  int idx = blockIdx.x * 64 + threadIdx.x;
  if (idx >= N_GRAPHS * OUT_DIM) return;
  int g = idx >> 4, j = idx & 15;
  float acc = b1[j];
  const float* mr = m0 + g * HIDDEN;
  for (int k = 0; k < HIDDEN; ++k) acc += mr[k] * W1[k * OUT_DIM + j];
  out[idx] = fmaxf(acc, 0.f);
}

// ---------------- launch ----------------
extern "C" void kernel_launch(void* const* d_in, const int* in_sizes, int n_in,
                              void* d_out, int out_size, void* d_ws, size_t ws_size,
                              hipStream_t stream) {
  const float* x_in   = (const float*)d_in[0];
  const float* ea_in  = (const float*)d_in[1];
  const int*   ei     = (const int*)d_in[2];
  const int*   batch  = (const int*)d_in[3];
  const float* W_lin  = (const float*)d_in[4];
  const float* b_lin  = (const float*)d_in[5];
  const float* W_root = (const float*)d_in[6];
  const float* W_edge = (const float*)d_in[7];
  const float* b_edge = (const float*)d_in[8];
  const float* W0     = (const float*)d_in[9];
  const float* b0     = (const float*)d_in[10];
  const float* W1     = (const float*)d_in[11];
  const float* b1     = (const float*)d_in[12];
  const int* row = ei;
  const int* col = ei + N_EDGES;

  float* out0 = (float*)d_out;                  // [256,16]
  float* embN = out0 + N_GRAPHS * OUT_DIM;      // [50000,128] final pre-relu MFConv out
  float* embE = embN + (size_t)N_NODES * DIM;   // [600000,128] final pre-relu EdgeConv out

  char* wsp = (char*)d_ws;
  auto alloc = [&](size_t bytes) {
    char* p = wsp;
    wsp += (bytes + 255) & ~(size_t)255;
    return p;
  };
  int* deg      = (int*)alloc((size_t)N_NODES * 4);
  int* rowptr   = (int*)alloc((size_t)(N_NODES + 1) * 4);
  int* cursor   = (int*)alloc((size_t)N_NODES * 4);
  int* src      = (int*)alloc((size_t)N_EDGES * 4);
  int* nlist    = (int*)alloc((size_t)N_NODES * 4);
  int* bcur     = (int*)alloc(16 * 4);
  int* tbl_d    = (int*)alloc(MAX_TBL * 4);
  int* tbl_base = (int*)alloc(MAX_TBL * 4);
  int* tbl_cnt  = (int*)alloc(MAX_TBL * 4);
  int* gstart   = (int*)alloc(257 * 4);
  float* tmpNr  = (float*)alloc((size_t)N_NODES * DIM * 4);  // relu(pass0 MFConv out)
  float* Em0    = (float*)alloc((size_t)N_NODES * DIM * 4);  // pass0 EdgeConv out
  float* Bm     = (float*)alloc((size_t)N_NODES * DIM * 4);
  float* Cm     = (float*)alloc((size_t)N_NODES * DIM * 4);
  float* h      = (float*)alloc((size_t)N_NODES * DIM * 4);  // readout node gather
  float* gf     = (float*)alloc((size_t)N_GRAPHS * 256 * 4);
  float* m0     = (float*)alloc((size_t)N_GRAPHS * HIDDEN * 4);

  hipMemsetAsync(deg, 0, (size_t)N_NODES * 4, stream);
  // emb_edge rows [50000, 600000) are exactly 0 (empty segment-max -> where -> 0)
  hipMemsetAsync(embE + (size_t)N_NODES * DIM, 0,
                 (size_t)(N_EDGES - N_NODES) * DIM * sizeof(float), stream);

  const int EB = (N_EDGES + 255) / 256;
  const int NB = (N_NODES + 255) / 256;
  k_deg_count<<<EB, 256, 0, stream>>>(col, deg);
  k_setup<<<1, 1024, 0, stream>>>(deg, batch, rowptr, cursor, bcur,
                                  tbl_d, tbl_base, tbl_cnt, gstart);
  k_scatter_fused<<<NB + EB, 256, 0, stream>>>(row, col, cursor, src, deg, bcur, nlist);

  const int AGG_GRID = (N_NODES + 3) / 4;
  const int GEMM_GRID = (N_NODES + 31) / 32;
  // ---- message pass 0 (store relu'd node features; pre-relu pass0 tensor is unused) ----
  kMF_fused<true><<<MAX_TBL, 128, 0, stream>>>(x_in, W_lin, b_lin, W_root,
                                               rowptr, src, tbl_d, tbl_base, tbl_cnt,
                                               nlist, tmpNr);
  kEG_gemm<false><<<GEMM_GRID, 128, 0, stream>>>(ea_in, W_edge, Bm, Cm);
  kEA_aggr<<<AGG_GRID, 128, 0, stream>>>(Bm, Cm, b_edge, deg, rowptr, src, Em0);
  // ---- message pass 1 (inputs pre-activated; outputs are the emb tensors) ----
  kMF_fused<false><<<MAX_TBL, 128, 0, stream>>>(tmpNr, W_lin, b_lin, W_root,
                                                rowptr, src, tbl_d, tbl_base, tbl_cnt,
                                                nlist, embN);
  kEG_gemm<true><<<GEMM_GRID, 128, 0, stream>>>(Em0, W_edge, Bm, Cm);
  kEA_aggr<<<AGG_GRID, 128, 0, stream>>>(Bm, Cm, b_edge, deg, rowptr, src, embE);
  // ---- readout ----
  kA_final<<<AGG_GRID, 128, 0, stream>>>(embN, rowptr, src, h);
  k_pool<<<N_GRAPHS, 256, 0, stream>>>(h, embE, deg, gstart, gf);
  k_mlp0<<<N_GRAPHS, 256, 0, stream>>>(gf, W0, b0, m0);
  k_mlp1<<<(N_GRAPHS * OUT_DIM + 63) / 64, 64, 0, stream>>>(m0, W1, b1, out0);
}

// Round 2
// 1325.837 us; speedup vs baseline: 1.0874x; 1.0802x over previous
//
#include <hip/hip_runtime.h>
#include <cfloat>

#define N_NODES 50000
#define N_EDGES 600000
#define DIM 128
#define N_GRAPHS 256
#define HIDDEN 256
#define OUT_DIM 16
#define MAX_DEG 10
#define MAX_TBL 1600
#define GEMM_GRID 1563  // (N_NODES+31)/32
#define AGG_GRID 12500  // (N_NODES+3)/4
#define EB 2344         // (N_EDGES+255)/256
#define NB 196          // (N_NODES+255)/256

__device__ __forceinline__ float4 relu4(float4 v) {
  return make_float4(fmaxf(v.x, 0.f), fmaxf(v.y, 0.f), fmaxf(v.z, 0.f), fmaxf(v.w, 0.f));
}
__device__ __forceinline__ void fma4(float4& a, float m, const float4 v) {
  a.x = fmaf(m, v.x, a.x); a.y = fmaf(m, v.y, a.y);
  a.z = fmaf(m, v.z, a.z); a.w = fmaf(m, v.w, a.w);
}
__device__ __forceinline__ void max4(float4& a, const float4 v) {
  a.x = fmaxf(a.x, v.x); a.y = fmaxf(a.y, v.y);
  a.z = fmaxf(a.z, v.z); a.w = fmaxf(a.w, v.w);
}

// ---------------- setup: scan + histogram + bucket table + graph bounds ----------------
__global__ void k_setup(const int* __restrict__ deg, const int* __restrict__ batch,
                        int* __restrict__ rowptr, int* __restrict__ cursor,
                        int* __restrict__ bcur, int* __restrict__ tbl_d,
                        int* __restrict__ tbl_base, int* __restrict__ tbl_cnt,
                        int* __restrict__ gstart) {
  __shared__ int tsum[1024];
  __shared__ int hist[MAX_DEG + 1];
  __shared__ int boff[MAX_DEG + 1];
  __shared__ int tblStart[MAX_DEG + 2];
  const int CH = (N_NODES + 1023) / 1024;  // 49
  int t = threadIdx.x;
  if (t <= MAX_DEG) hist[t] = 0;
  __syncthreads();
  for (int base2 = 0; base2 < N_NODES; base2 += 1024) {
    int i = base2 + t;
    int d = (i < N_NODES) ? min(deg[i], MAX_DEG) : -1;
#pragma unroll
    for (int dd = 0; dd <= MAX_DEG; ++dd) {
      unsigned long long m = __ballot(d == dd);
      if ((t & 63) == 0 && m) atomicAdd(&hist[dd], (int)__popcll(m));
    }
  }
  int lo = t * CH, hi = min(lo + CH, N_NODES);
  int s = 0;
  for (int i = lo; i < hi; ++i) s += deg[i];
  tsum[t] = s;
  __syncthreads();
  for (int off = 1; off < 1024; off <<= 1) {
    int v = (t >= off) ? tsum[t - off] : 0;
    __syncthreads();
    tsum[t] += v;
    __syncthreads();
  }
  int pre = (t == 0) ? 0 : tsum[t - 1];
  for (int i = lo; i < hi; ++i) { rowptr[i] = pre; cursor[i] = pre; pre += deg[i]; }
  if (t == 1023) rowptr[N_NODES] = tsum[1023];
  if (t == 0) {
    int off = 0, nb = 0;
    for (int d = 0; d <= MAX_DEG; ++d) {
      boff[d] = off; bcur[d] = off; off += hist[d];
      tblStart[d] = nb; nb += (hist[d] + 31) / 32;
    }
    tblStart[MAX_DEG + 1] = nb;
  }
  __syncthreads();
  int totalb = tblStart[MAX_DEG + 1];
  for (int d = 0; d <= MAX_DEG; ++d) {
    int nblk = (hist[d] + 31) / 32;
    int st = tblStart[d];
    for (int idx = t; idx < nblk; idx += 1024) {
      tbl_d[st + idx] = d;
      tbl_base[st + idx] = boff[d] + idx * 32;
      tbl_cnt[st + idx] = min(32, hist[d] - idx * 32);
    }
  }
  for (int idx = totalb + t; idx < MAX_TBL; idx += 1024) tbl_d[idx] = -1;
  for (int g = t; g <= N_GRAPHS; g += 1024) {
    int lo2 = 0, hi2 = N_NODES;
    while (lo2 < hi2) {
      int mid = (lo2 + hi2) >> 1;
      if (batch[mid] < g) lo2 = mid + 1; else hi2 = mid;
    }
    gstart[g] = lo2;
  }
}

// ---------------- fused CSR edge scatter + bucket node scatter ----------------
__global__ void k_scatter_fused(const int* __restrict__ row, const int* __restrict__ col,
                                int* __restrict__ cursor, int* __restrict__ src,
                                const int* __restrict__ deg, int* __restrict__ bcur,
                                int* __restrict__ nlist) {
  int b = blockIdx.x;
  if (b < NB) {
    __shared__ int lh[MAX_DEG + 1];
    __shared__ int gbase[MAX_DEG + 1];
    int t = threadIdx.x;
    if (t <= MAX_DEG) lh[t] = 0;
    __syncthreads();
    int i = b * 256 + t;
    int bk = 0, r = 0;
    if (i < N_NODES) { bk = min(deg[i], MAX_DEG); r = atomicAdd(&lh[bk], 1); }
    __syncthreads();
    if (t <= MAX_DEG) gbase[t] = lh[t] ? atomicAdd(&bcur[t], lh[t]) : 0;
    __syncthreads();
    if (i < N_NODES) nlist[gbase[bk] + r] = i;
  } else {
    int e = (b - NB) * 256 + threadIdx.x;
    if (e < N_EDGES) {
      int p = atomicAdd(&cursor[col[e]], 1);
      src[p] = row[e];
    }
  }
}

// ---------------- device bodies (256 threads each) ----------------
// MFConv: gather-sum neighbors (8 wave-groups of 32) + degree-bucketed matvec
template <bool RELU_STORE>
__device__ __forceinline__ void dev_MF_body(
    int b, const float* __restrict__ x, const float* __restrict__ W_lin,
    const float* __restrict__ b_lin, const float* __restrict__ W_root,
    const int* __restrict__ rowptr, const int* __restrict__ src,
    const int* __restrict__ tbl_d, const int* __restrict__ tbl_base,
    const int* __restrict__ tbl_cnt, const int* __restrict__ nlist,
    float* __restrict__ out, float* hs /*32*DIM*/, int* nid /*32*/) {
  int d = tbl_d[b];
  if (d < 0) return;  // block-uniform
  int base = tbl_base[b], cnt = tbl_cnt[b];
  int tid = threadIdx.x;
  if (tid < 32) nid[tid] = nlist[base + min(tid, cnt - 1)];
  __syncthreads();
  int q = tid >> 5, l = tid & 31;
  for (int i = q; i < 32; i += 8) {
    int node = nid[i];
    int s = rowptr[node], e = rowptr[node + 1], e1 = e - 1;
    float4 a = make_float4(0.f, 0.f, 0.f, 0.f);
    for (int p = s; p < e; p += 8) {
      int idx[8]; float msk[8];
#pragma unroll
      for (int u = 0; u < 8; ++u) {
        int pe = p + u;
        idx[u] = src[min(pe, e1)];
        msk[u] = (pe < e) ? 1.f : 0.f;
      }
#pragma unroll
      for (int u = 0; u < 8; ++u)
        fma4(a, msk[u], ((const float4*)(x + (size_t)idx[u] * DIM))[l]);
    }
    ((float4*)(hs + i * DIM))[l] = a;
  }
  __syncthreads();
  int half = tid >> 7, j = tid & 127;
  const float* Wl = W_lin + (size_t)d * DIM * DIM + j;
  const float* Wr = W_root + (size_t)d * DIM * DIM + j;
  float bl = b_lin[d * DIM + j];
  float acc[16]; int off[16];
#pragma unroll
  for (int ii = 0; ii < 16; ++ii) { acc[ii] = bl; off[ii] = nid[half * 16 + ii] * DIM; }
  for (int k = 0; k < DIM; k += 4) {
    float wl0 = Wl[(k + 0) * DIM], wl1 = Wl[(k + 1) * DIM];
    float wl2 = Wl[(k + 2) * DIM], wl3 = Wl[(k + 3) * DIM];
    float wr0 = Wr[(k + 0) * DIM], wr1 = Wr[(k + 1) * DIM];
    float wr2 = Wr[(k + 2) * DIM], wr3 = Wr[(k + 3) * DIM];
#pragma unroll
    for (int ii = 0; ii < 16; ++ii) {
      const float4 hv = *(const float4*)(hs + (half * 16 + ii) * DIM + k);  // LDS broadcast
      const float4 xv = *(const float4*)(x + off[ii] + k);                  // global L1 broadcast
      acc[ii] += hv.x * wl0 + hv.y * wl1 + hv.z * wl2 + hv.w * wl3 +
                 xv.x * wr0 + xv.y * wr1 + xv.z * wr2 + xv.w * wr3;
    }
  }
#pragma unroll
  for (int ii = 0; ii < 16; ++ii) {
    int i = half * 16 + ii;
    if (i < cnt) {
      float v = acc[ii];
      if (RELU_STORE) v = fmaxf(v, 0.f);
      out[(size_t)nid[i] * DIM + j] = v;
    }
  }
}

// EdgeConv GEMM: B = e@W_bot, C = e@(W_top - W_bot)  (256 threads, 32 rows/block)
template <bool RELU>
__device__ __forceinline__ void dev_EG_body(int bid, const float* __restrict__ e,
                                            const float* __restrict__ W,
                                            float* __restrict__ Bm, float* __restrict__ Cm,
                                            float* es /*32*DIM*/) {
  int base = bid * 32;
  int tid = threadIdx.x, half = tid >> 7, j = tid & 127;
  int cnt = min(32, N_NODES - base);
#pragma unroll
  for (int ii = 0; ii < 16; ++ii) {
    int i = half * 16 + ii;
    int r = base + min(i, cnt - 1);
    float v = e[(size_t)r * DIM + j];
    if (RELU) v = fmaxf(v, 0.f);
    es[i * DIM + j] = v;
  }
  __syncthreads();
  float accB[16], accC[16];
#pragma unroll
  for (int ii = 0; ii < 16; ++ii) { accB[ii] = 0.f; accC[ii] = 0.f; }
  const float* Wt = W + j;
  const float* Wb = W + 128 * DIM + j;
  for (int k = 0; k < DIM; k += 4) {
    float wb0 = Wb[(k + 0) * DIM], wb1 = Wb[(k + 1) * DIM];
    float wb2 = Wb[(k + 2) * DIM], wb3 = Wb[(k + 3) * DIM];
    float wd0 = Wt[(k + 0) * DIM] - wb0, wd1 = Wt[(k + 1) * DIM] - wb1;
    float wd2 = Wt[(k + 2) * DIM] - wb2, wd3 = Wt[(k + 3) * DIM] - wb3;
#pragma unroll
    for (int ii = 0; ii < 16; ++ii) {
      const float4 ev = *(const float4*)(es + (half * 16 + ii) * DIM + k);
      accB[ii] += ev.x * wb0 + ev.y * wb1 + ev.z * wb2 + ev.w * wb3;
      accC[ii] += ev.x * wd0 + ev.y * wd1 + ev.z * wd2 + ev.w * wd3;
    }
  }
#pragma unroll
  for (int ii = 0; ii < 16; ++ii) {
    int i = half * 16 + ii;
    if (i < cnt) {
      Bm[(size_t)(base + i) * DIM + j] = accB[ii];
      Cm[(size_t)(base + i) * DIM + j] = accC[ii];
    }
  }
}

// Edge aggregation (max), optionally fused with readout node gather-sum.
// Wave-per-node: 64 lanes = 2 edges x 32 lanes; halves combined via shfl_xor(32).
template <bool WITH_H>
__device__ __forceinline__ void dev_EA_body(
    int bid, const float* __restrict__ Bm, const float* __restrict__ Cm,
    const float* __restrict__ b_edge, const int* __restrict__ deg,
    const int* __restrict__ rowptr, const int* __restrict__ src,
    const float* __restrict__ embN, float* __restrict__ out, float* __restrict__ h) {
  int w = threadIdx.x >> 6;
  int node = bid * 4 + w;
  if (node >= N_NODES) return;
  int l = threadIdx.x & 63, half = l >> 5, lr = l & 31;
  if (deg[node] == 0) {
    if (half == 0) {
      ((float4*)(out + (size_t)node * DIM))[lr] = make_float4(0.f, 0.f, 0.f, 0.f);
      if (WITH_H) ((float4*)(h + (size_t)node * DIM))[lr] = make_float4(0.f, 0.f, 0.f, 0.f);
    }
    return;
  }
  int s = rowptr[node], e = rowptr[node + 1], e1 = e - 1;
  float4 m = make_float4(-FLT_MAX, -FLT_MAX, -FLT_MAX, -FLT_MAX);
  float4 a = make_float4(0.f, 0.f, 0.f, 0.f);
  for (int p = s; p < e; p += 8) {
    int idx[4]; float msk[4];
#pragma unroll
    for (int u = 0; u < 4; ++u) {
      int pe = p + 2 * u + half;
      idx[u] = src[min(pe, e1)];
      msk[u] = (pe < e) ? 1.f : 0.f;
    }
#pragma unroll
    for (int u = 0; u < 4; ++u) {
      max4(m, ((const float4*)(Bm + (size_t)idx[u] * DIM))[lr]);  // dup-clamp safe for max
      if (WITH_H) {
        float4 v = relu4(((const float4*)(embN + (size_t)idx[u] * DIM))[lr]);
        fma4(a, msk[u], v);
      }
    }
  }
  m.x = fmaxf(m.x, __shfl_xor(m.x, 32));
  m.y = fmaxf(m.y, __shfl_xor(m.y, 32));
  m.z = fmaxf(m.z, __shfl_xor(m.z, 32));
  m.w = fmaxf(m.w, __shfl_xor(m.w, 32));
  if (WITH_H) {
    a.x += __shfl_xor(a.x, 32);
    a.y += __shfl_xor(a.y, 32);
    a.z += __shfl_xor(a.z, 32);
    a.w += __shfl_xor(a.w, 32);
  }
  if (half == 0) {
    const float4 c = ((const float4*)(Cm + (size_t)node * DIM))[lr];
    const float4 be = ((const float4*)b_edge)[lr];
    ((float4*)(out + (size_t)node * DIM))[lr] =
        make_float4(c.x + be.x + m.x, c.y + be.y + m.y, c.z + be.z + m.z, c.w + be.w + m.w);
    if (WITH_H) ((float4*)(h + (size_t)node * DIM))[lr] = a;
  }
}

// ---------------- fused dispatches ----------------
// A: EdgeConv pass-0 GEMM (no CSR needed)  ||  degree count
__global__ __launch_bounds__(256) void kA(const int* __restrict__ col, int* __restrict__ deg,
                                          const float* __restrict__ ea,
                                          const float* __restrict__ W_edge,
                                          float* __restrict__ Bm, float* __restrict__ Cm) {
  __shared__ float sm[32 * DIM];
  if (blockIdx.x < GEMM_GRID) {
    dev_EG_body<false>(blockIdx.x, ea, W_edge, Bm, Cm, sm);
  } else {
    int e = (blockIdx.x - GEMM_GRID) * 256 + threadIdx.x;
    if (e < N_EDGES) atomicAdd(&deg[col[e]], 1);
  }
}

// D: MFConv pass-0 (gather+matvec)  ||  EdgeConv pass-0 aggregation
__global__ __launch_bounds__(256) void kD(
    const float* __restrict__ x, const float* __restrict__ W_lin,
    const float* __restrict__ b_lin, const float* __restrict__ W_root,
    const int* __restrict__ rowptr, const int* __restrict__ src,
    const int* __restrict__ tbl_d, const int* __restrict__ tbl_base,
    const int* __restrict__ tbl_cnt, const int* __restrict__ nlist,
    float* __restrict__ tmpNr,
    const float* __restrict__ Bm, const float* __restrict__ Cm,
    const float* __restrict__ b_edge, const int* __restrict__ deg,
    float* __restrict__ Em0) {
  __shared__ float sm[32 * DIM];
  __shared__ int nid[32];
  if (blockIdx.x < MAX_TBL)
    dev_MF_body<true>(blockIdx.x, x, W_lin, b_lin, W_root, rowptr, src,
                      tbl_d, tbl_base, tbl_cnt, nlist, tmpNr, sm, nid);
  else
    dev_EA_body<false>(blockIdx.x - MAX_TBL, Bm, Cm, b_edge, deg, rowptr, src,
                       nullptr, Em0, nullptr);
}

// E: MFConv pass-1  ||  EdgeConv pass-1 GEMM
__global__ __launch_bounds__(256) void kE(
    const float* __restrict__ tmpNr, const float* __restrict__ W_lin,
    const float* __restrict__ b_lin, const float* __restrict__ W_root,
    const int* __restrict__ rowptr, const int* __restrict__ src,
    const int* __restrict__ tbl_d, const int* __restrict__ tbl_base,
    const int* __restrict__ tbl_cnt, const int* __restrict__ nlist,
    float* __restrict__ embN,
    const float* __restrict__ Em0, const float* __restrict__ W_edge,
    float* __restrict__ Bm, float* __restrict__ Cm) {
  __shared__ float sm[32 * DIM];
  __shared__ int nid[32];
  if (blockIdx.x < MAX_TBL)
    dev_MF_body<false>(blockIdx.x, tmpNr, W_lin, b_lin, W_root, rowptr, src,
                       tbl_d, tbl_base, tbl_cnt, nlist, embN, sm, nid);
  else
    dev_EG_body<true>(blockIdx.x - MAX_TBL, Em0, W_edge, Bm, Cm, sm);
}

// F: EdgeConv pass-1 aggregation + readout node gather (shared CSR walk)
__global__ __launch_bounds__(256) void kF(
    const float* __restrict__ Bm, const float* __restrict__ Cm,
    const float* __restrict__ b_edge, const int* __restrict__ deg,
    const int* __restrict__ rowptr, const int* __restrict__ src,
    const float* __restrict__ embN, float* __restrict__ embE, float* __restrict__ h) {
  dev_EA_body<true>(blockIdx.x, Bm, Cm, b_edge, deg, rowptr, src, embN, embE, h);
}

// G: pool + mlp0 + mlp1 fused (one block per graph)
__global__ __launch_bounds__(256) void k_readout(
    const float* __restrict__ hf, const float* __restrict__ embE,
    const int* __restrict__ deg, const int* __restrict__ gstart,
    const float* __restrict__ W0, const float* __restrict__ b0,
    const float* __restrict__ W1, const float* __restrict__ b1,
    float* __restrict__ out0) {
  __shared__ float gs[256];
  __shared__ float hid[256];
  int g = blockIdx.x, j = threadIdx.x;
  int s = gstart[g], e = gstart[g + 1];
  float acc = 0.f;
  if (j < DIM) {
    for (int i = s; i < e; ++i) acc += hf[(size_t)i * DIM + j];
  } else {
    int jj = j - DIM;
    for (int i = s; i < e; ++i)
      acc += (float)deg[i] * fmaxf(embE[(size_t)i * DIM + jj], 0.f);
  }
  gs[j] = acc;
  __syncthreads();
  float a0 = b0[j];
  for (int k = 0; k < 256; ++k) a0 += gs[k] * W0[k * 256 + j];
  hid[j] = fmaxf(a0, 0.f);
  __syncthreads();
  if (j < OUT_DIM) {
    float a1 = b1[j];
    for (int k = 0; k < HIDDEN; ++k) a1 += hid[k] * W1[k * OUT_DIM + j];
    out0[g * OUT_DIM + j] = fmaxf(a1, 0.f);
  }
}

// ---------------- launch ----------------
extern "C" void kernel_launch(void* const* d_in, const int* in_sizes, int n_in,
                              void* d_out, int out_size, void* d_ws, size_t ws_size,
                              hipStream_t stream) {
  const float* x_in   = (const float*)d_in[0];
  const float* ea_in  = (const float*)d_in[1];
  const int*   ei     = (const int*)d_in[2];
  const int*   batch  = (const int*)d_in[3];
  const float* W_lin  = (const float*)d_in[4];
  const float* b_lin  = (const float*)d_in[5];
  const float* W_root = (const float*)d_in[6];
  const float* W_edge = (const float*)d_in[7];
  const float* b_edge = (const float*)d_in[8];
  const float* W0     = (const float*)d_in[9];
  const float* b0     = (const float*)d_in[10];
  const float* W1     = (const float*)d_in[11];
  const float* b1     = (const float*)d_in[12];
  const int* row = ei;
  const int* col = ei + N_EDGES;

  float* out0 = (float*)d_out;                  // [256,16]
  float* embN = out0 + N_GRAPHS * OUT_DIM;      // [50000,128] final pre-relu MFConv out
  float* embE = embN + (size_t)N_NODES * DIM;   // [600000,128] final pre-relu EdgeConv out

  char* wsp = (char*)d_ws;
  auto alloc = [&](size_t bytes) {
    char* p = wsp;
    wsp += (bytes + 255) & ~(size_t)255;
    return p;
  };
  int* deg      = (int*)alloc((size_t)N_NODES * 4);
  int* rowptr   = (int*)alloc((size_t)(N_NODES + 1) * 4);
  int* cursor   = (int*)alloc((size_t)N_NODES * 4);
  int* src      = (int*)alloc((size_t)N_EDGES * 4);
  int* nlist    = (int*)alloc((size_t)N_NODES * 4);
  int* bcur     = (int*)alloc(16 * 4);
  int* tbl_d    = (int*)alloc(MAX_TBL * 4);
  int* tbl_base = (int*)alloc(MAX_TBL * 4);
  int* tbl_cnt  = (int*)alloc(MAX_TBL * 4);
  int* gstart   = (int*)alloc(257 * 4);
  float* tmpNr  = (float*)alloc((size_t)N_NODES * DIM * 4);  // relu(pass0 MFConv out)
  float* Em0    = (float*)alloc((size_t)N_NODES * DIM * 4);  // pass0 EdgeConv out (pre-relu)
  float* Bm     = (float*)alloc((size_t)N_NODES * DIM * 4);
  float* Cm     = (float*)alloc((size_t)N_NODES * DIM * 4);
  float* h      = (float*)alloc((size_t)N_NODES * DIM * 4);  // readout node gather

  hipMemsetAsync(deg, 0, (size_t)N_NODES * 4, stream);
  // emb_edge rows [50000, 600000) are exactly 0 (empty segment-max -> where -> 0)
  hipMemsetAsync(embE + (size_t)N_NODES * DIM, 0,
                 (size_t)(N_EDGES - N_NODES) * DIM * sizeof(float), stream);

  // A: EdgeConv0 GEMM || deg count (independent)
  kA<<<GEMM_GRID + EB, 256, 0, stream>>>(col, deg, ea_in, W_edge, Bm, Cm);
  // B: CSR scan + buckets + graph bounds
  k_setup<<<1, 1024, 0, stream>>>(deg, batch, rowptr, cursor, bcur,
                                  tbl_d, tbl_base, tbl_cnt, gstart);
  // C: edge scatter + node scatter
  k_scatter_fused<<<NB + EB, 256, 0, stream>>>(row, col, cursor, src, deg, bcur, nlist);
  // D: MFConv0 || EdgeConv0 aggregation
  kD<<<MAX_TBL + AGG_GRID, 256, 0, stream>>>(x_in, W_lin, b_lin, W_root, rowptr, src,
                                             tbl_d, tbl_base, tbl_cnt, nlist, tmpNr,
                                             Bm, Cm, b_edge, deg, Em0);
  // E: MFConv1 || EdgeConv1 GEMM
  kE<<<MAX_TBL + GEMM_GRID, 256, 0, stream>>>(tmpNr, W_lin, b_lin, W_root, rowptr, src,
                                              tbl_d, tbl_base, tbl_cnt, nlist, embN,
                                              Em0, W_edge, Bm, Cm);
  // F: EdgeConv1 aggregation + readout node gather (one CSR walk)
  kF<<<AGG_GRID, 256, 0, stream>>>(Bm, Cm, b_edge, deg, rowptr, src, embN, embE, h);
  // G: pool + MLP
  k_readout<<<N_GRAPHS, 256, 0, stream>>>(h, embE, deg, gstart, W0, b0, W1, b1, out0);
}

// Round 3
// 913.468 us; speedup vs baseline: 1.5782x; 1.4514x over previous
//
#include <hip/hip_runtime.h>
#include <cfloat>

#define N_NODES 50000
#define N_EDGES 600000
#define DIM 128
#define N_GRAPHS 256
#define HIDDEN 256
#define OUT_DIM 16
#define MAX_DEG 10
#define MAX_TBL 1600
#define GEMM_GRID 1563  // (N_NODES+31)/32
#define AGG_GRID 12500  // (N_NODES+3)/4
#define EB 2344         // (N_EDGES+255)/256
#define NB 196          // (N_NODES+255)/256
#define XCONV_B 6250    // 50000*128/4/256
#define WF_B 176        // 11*8*8*64/256
#define WEF_B 16        // 4*16*64/256

typedef unsigned short u16;
typedef __attribute__((ext_vector_type(8))) short bf16x8;
typedef __attribute__((ext_vector_type(4))) float f32x4;

__device__ __forceinline__ float bf2f(u16 u) {
  union { unsigned u; float f; } c; c.u = ((unsigned)u) << 16; return c.f;
}
__device__ __forceinline__ u16 f2bf(float f) {
  union { float f; unsigned u; } c; c.f = f;
  return (u16)((c.u + 0x7FFFu + ((c.u >> 16) & 1u)) >> 16);
}
__device__ __forceinline__ float4 relu4(float4 v) {
  return make_float4(fmaxf(v.x, 0.f), fmaxf(v.y, 0.f), fmaxf(v.z, 0.f), fmaxf(v.w, 0.f));
}
__device__ __forceinline__ void fma4b(float4& a, float m, ushort4 v) {
  a.x = fmaf(m, bf2f(v.x), a.x); a.y = fmaf(m, bf2f(v.y), a.y);
  a.z = fmaf(m, bf2f(v.z), a.z); a.w = fmaf(m, bf2f(v.w), a.w);
}
__device__ __forceinline__ void max4b(float4& a, ushort4 v) {
  a.x = fmaxf(a.x, bf2f(v.x)); a.y = fmaxf(a.y, bf2f(v.y));
  a.z = fmaxf(a.z, bf2f(v.z)); a.w = fmaxf(a.w, bf2f(v.w));
}

// ---------------- prep: x->bf16, weight fragment pre-swizzle, deg count ----------------
// Wfrag[d][ks(8)][nt(8)][lane(64)][8]: lane l holds B[k=ks*32+(l>>4)*8+j][n=nt*16+(l&15)]
// where B rows k<128 = W_lin[d], k>=128 = W_root[d]  (A = [h | x] concat over K=256)
// Wefrag[ks(4)][nt(16)][lane(64)][8]: n2<128 -> W_edge[128+k][n2] (Bm out);
//   n2>=128 -> W_edge[k][n2-128]-W_edge[128+k][n2-128] (Cm out)
__global__ __launch_bounds__(256) void kPrep(
    const float* __restrict__ x_in, u16* __restrict__ xb,
    const float* __restrict__ W_lin, const float* __restrict__ W_root,
    u16* __restrict__ Wfrag, const float* __restrict__ W_edge,
    u16* __restrict__ Wefrag, const int* __restrict__ col, int* __restrict__ deg) {
  int b = blockIdx.x, t = threadIdx.x;
  if (b < XCONV_B) {
    size_t i = ((size_t)b * 256 + t) * 4;
    float4 v = *(const float4*)(x_in + i);
    ushort4 o; o.x = f2bf(v.x); o.y = f2bf(v.y); o.z = f2bf(v.z); o.w = f2bf(v.w);
    *(ushort4*)(xb + i) = o;
  } else if (b < XCONV_B + WF_B) {
    int tid = (b - XCONV_B) * 256 + t;
    int lane = tid & 63, f = tid >> 6;        // f < 704 = 11*64
    int d = f >> 6, rem = f & 63, ks = rem >> 3, nt = rem & 7;
    u16* dst = Wfrag + ((size_t)f * 64 + lane) * 8;
    int n = nt * 16 + (lane & 15);
#pragma unroll
    for (int j = 0; j < 8; ++j) {
      int k = ks * 32 + (lane >> 4) * 8 + j;
      float v = (k < 128) ? W_lin[((size_t)d * 128 + k) * 128 + n]
                          : W_root[((size_t)d * 128 + (k - 128)) * 128 + n];
      dst[j] = f2bf(v);
    }
  } else if (b < XCONV_B + WF_B + WEF_B) {
    int tid = (b - XCONV_B - WF_B) * 256 + t;  // < 4096
    int lane = tid & 63, f = tid >> 6;         // f < 64
    int ks = f >> 4, nt = f & 15;
    u16* dst = Wefrag + ((size_t)f * 64 + lane) * 8;
    int n2 = nt * 16 + (lane & 15);
#pragma unroll
    for (int j = 0; j < 8; ++j) {
      int k = ks * 32 + (lane >> 4) * 8 + j;
      float v;
      if (n2 < 128) v = W_edge[(size_t)(128 + k) * 128 + n2];
      else { int n = n2 - 128; v = W_edge[(size_t)k * 128 + n] - W_edge[(size_t)(128 + k) * 128 + n]; }
      dst[j] = f2bf(v);
    }
  } else {
    int e = (b - XCONV_B - WF_B - WEF_B) * 256 + t;
    if (e < N_EDGES) atomicAdd(&deg[col[e]], 1);
  }
}

// ---------------- setup: scan + histogram + bucket table + graph bounds ----------------
__global__ void k_setup(const int* __restrict__ deg, const int* __restrict__ batch,
                        int* __restrict__ rowptr, int* __restrict__ cursor,
                        int* __restrict__ bcur, int* __restrict__ tbl_d,
                        int* __restrict__ tbl_base, int* __restrict__ tbl_cnt,
                        int* __restrict__ gstart) {
  __shared__ int tsum[1024];
  __shared__ int hist[MAX_DEG + 1];
  __shared__ int boff[MAX_DEG + 1];
  __shared__ int tblStart[MAX_DEG + 2];
  const int CH = (N_NODES + 1023) / 1024;  // 49
  int t = threadIdx.x;
  if (t <= MAX_DEG) hist[t] = 0;
  __syncthreads();
  for (int base2 = 0; base2 < N_NODES; base2 += 1024) {
    int i = base2 + t;
    int d = (i < N_NODES) ? min(deg[i], MAX_DEG) : -1;
#pragma unroll
    for (int dd = 0; dd <= MAX_DEG; ++dd) {
      unsigned long long m = __ballot(d == dd);
      if ((t & 63) == 0 && m) atomicAdd(&hist[dd], (int)__popcll(m));
    }
  }
  int lo = t * CH, hi = min(lo + CH, N_NODES);
  int s = 0;
  for (int i = lo; i < hi; ++i) s += deg[i];
  tsum[t] = s;
  __syncthreads();
  for (int off = 1; off < 1024; off <<= 1) {
    int v = (t >= off) ? tsum[t - off] : 0;
    __syncthreads();
    tsum[t] += v;
    __syncthreads();
  }
  int pre = (t == 0) ? 0 : tsum[t - 1];
  for (int i = lo; i < hi; ++i) { rowptr[i] = pre; cursor[i] = pre; pre += deg[i]; }
  if (t == 1023) rowptr[N_NODES] = tsum[1023];
  if (t == 0) {
    int off = 0, nb = 0;
    for (int d = 0; d <= MAX_DEG; ++d) {
      boff[d] = off; bcur[d] = off; off += hist[d];
      tblStart[d] = nb; nb += (hist[d] + 31) / 32;
    }
    tblStart[MAX_DEG + 1] = nb;
  }
  __syncthreads();
  int totalb = tblStart[MAX_DEG + 1];
  for (int d = 0; d <= MAX_DEG; ++d) {
    int nblk = (hist[d] + 31) / 32;
    int st = tblStart[d];
    for (int idx = t; idx < nblk; idx += 1024) {
      tbl_d[st + idx] = d;
      tbl_base[st + idx] = boff[d] + idx * 32;
      tbl_cnt[st + idx] = min(32, hist[d] - idx * 32);
    }
  }
  for (int idx = totalb + t; idx < MAX_TBL; idx += 1024) tbl_d[idx] = -1;
  for (int g = t; g <= N_GRAPHS; g += 1024) {
    int lo2 = 0, hi2 = N_NODES;
    while (lo2 < hi2) {
      int mid = (lo2 + hi2) >> 1;
      if (batch[mid] < g) lo2 = mid + 1; else hi2 = mid;
    }
    gstart[g] = lo2;
  }
}

// ---------------- EdgeConv GEMM via MFMA (device body) ----------------
// out[32 x 256] = e[32 x 128] @ [W_bot | W_diff]; n2<128 -> Bm (bf16), else Cm (f32)
template <bool RELUIN, bool F32IN>
__device__ __forceinline__ void dev_EG_mfma(
    int bid, const float* __restrict__ ef, const u16* __restrict__ eb,
    const u16* __restrict__ Wefrag, u16* __restrict__ Bm, float* __restrict__ Cm,
    char* Es /*32*256B swizzled*/) {
  int base = bid * 32;
  int cnt = min(32, N_NODES - base);
  int tid = threadIdx.x;
  if (F32IN) {
    int i0 = tid >> 5, c4 = (tid & 31) * 4;
#pragma unroll
    for (int it = 0; it < 4; ++it) {
      int i = i0 + it * 8;
      int r = base + min(i, cnt - 1);
      float4 v = *(const float4*)(ef + (size_t)r * DIM + c4);
      if (RELUIN) v = relu4(v);
      ushort4 o; o.x = f2bf(v.x); o.y = f2bf(v.y); o.z = f2bf(v.z); o.w = f2bf(v.w);
      unsigned by = (unsigned)(i * 256 + c4 * 2) ^ (unsigned)((i & 7) << 4);
      *(ushort4*)(Es + by) = o;
    }
  } else {
    int i0 = tid >> 4, c8 = (tid & 15) * 8;
#pragma unroll
    for (int it = 0; it < 2; ++it) {
      int i = i0 + it * 16;
      int r = base + min(i, cnt - 1);
      ushort4 v0 = *(const ushort4*)(eb + (size_t)r * DIM + c8);
      ushort4 v1 = *(const ushort4*)(eb + (size_t)r * DIM + c8 + 4);
      if (RELUIN) {
        v0.x = (v0.x & 0x8000) ? 0 : v0.x; v0.y = (v0.y & 0x8000) ? 0 : v0.y;
        v0.z = (v0.z & 0x8000) ? 0 : v0.z; v0.w = (v0.w & 0x8000) ? 0 : v0.w;
        v1.x = (v1.x & 0x8000) ? 0 : v1.x; v1.y = (v1.y & 0x8000) ? 0 : v1.y;
        v1.z = (v1.z & 0x8000) ? 0 : v1.z; v1.w = (v1.w & 0x8000) ? 0 : v1.w;
      }
      unsigned by = (unsigned)(i * 256 + c8 * 2) ^ (unsigned)((i & 7) << 4);
      *(ushort4*)(Es + by) = v0;
      *(ushort4*)(Es + by + 8) = v1;
    }
  }
  __syncthreads();
  int w = tid >> 6, l = tid & 63, mtile = w & 1, g = w >> 1;
  int l4 = l >> 4, l16 = l & 15;
  f32x4 acc[8];
#pragma unroll
  for (int nt = 0; nt < 8; ++nt) acc[nt] = (f32x4){0.f, 0.f, 0.f, 0.f};
  for (int ks = 0; ks < 4; ++ks) {
    unsigned by = (unsigned)((mtile * 16 + l16) * 256 + ks * 64 + l4 * 16) ^
                  (unsigned)((l16 & 7) << 4);
    bf16x8 af = *(const bf16x8*)(Es + by);
#pragma unroll
    for (int nt = 0; nt < 8; ++nt) {
      int ntile = g * 8 + nt;
      bf16x8 bf = *(const bf16x8*)(Wefrag + (((size_t)ks * 16 + ntile) * 64 + l) * 8);
      acc[nt] = __builtin_amdgcn_mfma_f32_16x16x32_bf16(af, bf, acc[nt], 0, 0, 0);
    }
  }
#pragma unroll
  for (int nt = 0; nt < 8; ++nt) {
    int n2 = (g * 8 + nt) * 16 + l16;
#pragma unroll
    for (int r = 0; r < 4; ++r) {
      int rowi = mtile * 16 + l4 * 4 + r;
      if (rowi < cnt) {
        size_t node = base + rowi;
        if (n2 < 128) Bm[node * DIM + n2] = f2bf(acc[nt][r]);
        else Cm[node * DIM + (n2 - 128)] = acc[nt][r];
      }
    }
  }
}

// ---------------- fused scatter + EG0 ----------------
__global__ __launch_bounds__(256) void k_scatter_fused(
    const int* __restrict__ row, const int* __restrict__ col,
    int* __restrict__ cursor, int* __restrict__ src,
    const int* __restrict__ deg, int* __restrict__ bcur, int* __restrict__ nlist,
    const float* __restrict__ ea, const u16* __restrict__ Wefrag,
    u16* __restrict__ Bm, float* __restrict__ Cm) {
  __shared__ __align__(16) char sm[8192];
  __shared__ int lh[MAX_DEG + 1];
  __shared__ int gbase[MAX_DEG + 1];
  int b = blockIdx.x;
  if (b < NB) {
    int t = threadIdx.x;
    if (t <= MAX_DEG) lh[t] = 0;
    __syncthreads();
    int i = b * 256 + t;
    int bk = 0, r = 0;
    if (i < N_NODES) { bk = min(deg[i], MAX_DEG); r = atomicAdd(&lh[bk], 1); }
    __syncthreads();
    if (t <= MAX_DEG) gbase[t] = lh[t] ? atomicAdd(&bcur[t], lh[t]) : 0;
    __syncthreads();
    if (i < N_NODES) nlist[gbase[bk] + r] = i;
  } else if (b < NB + EB) {
    int e = (b - NB) * 256 + threadIdx.x;
    if (e < N_EDGES) {
      int p = atomicAdd(&cursor[col[e]], 1);
      src[p] = row[e];
    }
  } else {
    dev_EG_mfma<false, true>(b - NB - EB, ea, nullptr, Wefrag, Bm, Cm, sm);
  }
}

// ---------------- MFConv via MFMA (device body) ----------------
// A[32 x 256] = [h | x] (bf16, swizzled LDS), B = Wfrag[d], C-tile 32x128
// MODE 0: store bf16 relu -> outb only.  MODE 1: f32 raw -> outf AND bf16 relu -> outb.
template <int MODE>
__device__ __forceinline__ void dev_MF_mfma(
    int b, const u16* __restrict__ xb, const u16* __restrict__ Wfrag,
    const float* __restrict__ b_lin, const int* __restrict__ rowptr,
    const int* __restrict__ src, const int* __restrict__ tbl_d,
    const int* __restrict__ tbl_base, const int* __restrict__ tbl_cnt,
    const int* __restrict__ nlist, float* __restrict__ outf, u16* __restrict__ outb,
    char* As /*32*512B swizzled*/, int* nid) {
  int d = tbl_d[b];
  if (d < 0) return;
  int base = tbl_base[b], cnt = tbl_cnt[b];
  int tid = threadIdx.x;
  if (tid < 32) nid[tid] = nlist[base + min(tid, cnt - 1)];
  __syncthreads();
  int q = tid >> 5, lr = tid & 31;
  for (int i = q; i < 32; i += 8) {
    int node = nid[i];
    int s = rowptr[node], e = rowptr[node + 1], e1 = e - 1;
    float4 a = make_float4(0.f, 0.f, 0.f, 0.f);
    for (int p = s; p < e; p += 8) {
      int idx[8]; float msk[8];
#pragma unroll
      for (int u = 0; u < 8; ++u) {
        int pe = p + u;
        idx[u] = src[min(pe, e1)];
        msk[u] = (pe < e) ? 1.f : 0.f;
      }
#pragma unroll
      for (int u = 0; u < 8; ++u)
        fma4b(a, msk[u], *(const ushort4*)(xb + (size_t)idx[u] * DIM + 4 * lr));
    }
    ushort4 xv = *(const ushort4*)(xb + (size_t)node * DIM + 4 * lr);
    ushort4 hb; hb.x = f2bf(a.x); hb.y = f2bf(a.y); hb.z = f2bf(a.z); hb.w = f2bf(a.w);
    unsigned swz = (unsigned)((i & 7) << 4);
    *(ushort4*)(As + (((unsigned)(i * 512 + 8 * lr)) ^ swz)) = hb;
    *(ushort4*)(As + (((unsigned)(i * 512 + 256 + 8 * lr)) ^ swz)) = xv;
  }
  __syncthreads();
  int w = tid >> 6, l = tid & 63, mtile = w & 1, g = w >> 1;
  int l4 = l >> 4, l16 = l & 15;
  f32x4 acc[4];
#pragma unroll
  for (int nt = 0; nt < 4; ++nt) {
    float bv = b_lin[d * DIM + (g * 4 + nt) * 16 + l16];
    acc[nt] = (f32x4){bv, bv, bv, bv};
  }
  const u16* Wf = Wfrag + (size_t)d * 32768;  // 8ks*8nt*64*8
  for (int ks = 0; ks < 8; ++ks) {
    unsigned by = (unsigned)((mtile * 16 + l16) * 512 + ks * 64 + l4 * 16) ^
                  (unsigned)((l16 & 7) << 4);
    bf16x8 af = *(const bf16x8*)(As + by);
#pragma unroll
    for (int nt = 0; nt < 4; ++nt) {
      int ntile = g * 4 + nt;
      bf16x8 bf = *(const bf16x8*)(Wf + (((size_t)ks * 8 + ntile) * 64 + l) * 8);
      acc[nt] = __builtin_amdgcn_mfma_f32_16x16x32_bf16(af, bf, acc[nt], 0, 0, 0);
    }
  }
#pragma unroll
  for (int nt = 0; nt < 4; ++nt) {
    int n = (g * 4 + nt) * 16 + l16;
#pragma unroll
    for (int r = 0; r < 4; ++r) {
      int rowi = mtile * 16 + l4 * 4 + r;
      if (rowi < cnt) {
        float v = acc[nt][r];
        size_t o = (size_t)nid[rowi] * DIM + n;
        if (MODE == 1) { outf[o] = v; outb[o] = f2bf(fmaxf(v, 0.f)); }
        else outb[o] = f2bf(fmaxf(v, 0.f));
      }
    }
  }
}

// ---------------- Edge aggregation (bf16 gather), optional readout-h fusion ----------------
// OUTB: write Em0 bf16.  else: write embE f32 (+h if WITH_H).
template <bool OUTB, bool WITH_H>
__device__ __forceinline__ void dev_EA(
    int bid, const u16* __restrict__ Bm, const float* __restrict__ Cm,
    const float* __restrict__ b_edge, const int* __restrict__ deg,
    const int* __restrict__ rowptr, const int* __restrict__ src,
    const u16* __restrict__ embNb, u16* __restrict__ outb, float* __restrict__ outf,
    float* __restrict__ h) {
  int w = threadIdx.x >> 6;
  int node = bid * 4 + w;
  if (node >= N_NODES) return;
  int l = threadIdx.x & 63, half = l >> 5, lr = l & 31;
  if (deg[node] == 0) {
    if (half == 0) {
      if (OUTB) {
        ushort4 z; z.x = z.y = z.z = z.w = 0;
        *(ushort4*)(outb + (size_t)node * DIM + 4 * lr) = z;
      } else {
        ((float4*)(outf + (size_t)node * DIM))[lr] = make_float4(0.f, 0.f, 0.f, 0.f);
        if (WITH_H) ((float4*)(h + (size_t)node * DIM))[lr] = make_float4(0.f, 0.f, 0.f, 0.f);
      }
    }
    return;
  }
  int s = rowptr[node], e = rowptr[node + 1], e1 = e - 1;
  float4 m = make_float4(-FLT_MAX, -FLT_MAX, -FLT_MAX, -FLT_MAX);
  float4 a = make_float4(0.f, 0.f, 0.f, 0.f);
  for (int p = s; p < e; p += 8) {
    int idx[4]; float msk[4];
#pragma unroll
    for (int u = 0; u < 4; ++u) {
      int pe = p + 2 * u + half;
      idx[u] = src[min(pe, e1)];
      msk[u] = (pe < e) ? 1.f : 0.f;
    }
#pragma unroll
    for (int u = 0; u < 4; ++u) {
      max4b(m, *(const ushort4*)(Bm + (size_t)idx[u] * DIM + 4 * lr));  // dup-clamp safe
      if (WITH_H)
        fma4b(a, msk[u], *(const ushort4*)(embNb + (size_t)idx[u] * DIM + 4 * lr));
    }
  }
  m.x = fmaxf(m.x, __shfl_xor(m.x, 32));
  m.y = fmaxf(m.y, __shfl_xor(m.y, 32));
  m.z = fmaxf(m.z, __shfl_xor(m.z, 32));
  m.w = fmaxf(m.w, __shfl_xor(m.w, 32));
  if (WITH_H) {
    a.x += __shfl_xor(a.x, 32); a.y += __shfl_xor(a.y, 32);
    a.z += __shfl_xor(a.z, 32); a.w += __shfl_xor(a.w, 32);
  }
  if (half == 0) {
    const float4 c = ((const float4*)(Cm + (size_t)node * DIM))[lr];
    const float4 be = ((const float4*)b_edge)[lr];
    float4 o = make_float4(c.x + be.x + m.x, c.y + be.y + m.y,
                           c.z + be.z + m.z, c.w + be.w + m.w);
    if (OUTB) {
      ushort4 ob; ob.x = f2bf(o.x); ob.y = f2bf(o.y); ob.z = f2bf(o.z); ob.w = f2bf(o.w);
      *(ushort4*)(outb + (size_t)node * DIM + 4 * lr) = ob;
    } else {
      ((float4*)(outf + (size_t)node * DIM))[lr] = o;
      if (WITH_H) ((float4*)(h + (size_t)node * DIM))[lr] = a;
    }
  }
}

// ---------------- fused dispatches ----------------
// D: MFConv0 (xb -> tmpNr bf16 relu) || EdgeConv0 aggregation (Bm,Cm -> Em0 bf16)
__global__ __launch_bounds__(256) void kD(
    const u16* __restrict__ xb, const u16* __restrict__ Wfrag,
    const float* __restrict__ b_lin, const int* __restrict__ rowptr,
    const int* __restrict__ src, const int* __restrict__ tbl_d,
    const int* __restrict__ tbl_base, const int* __restrict__ tbl_cnt,
    const int* __restrict__ nlist, u16* __restrict__ tmpNr,
    const u16* __restrict__ Bm, const float* __restrict__ Cm,
    const float* __restrict__ b_edge, const int* __restrict__ deg,
    u16* __restrict__ Em0) {
  __shared__ __align__(16) char sm[16384];
  __shared__ int nid[32];
  if (blockIdx.x < MAX_TBL)
    dev_MF_mfma<0>(blockIdx.x, xb, Wfrag, b_lin, rowptr, src, tbl_d, tbl_base,
                   tbl_cnt, nlist, nullptr, tmpNr, sm, nid);
  else
    dev_EA<true, false>(blockIdx.x - MAX_TBL, Bm, Cm, b_edge, deg, rowptr, src,
                        nullptr, Em0, nullptr, nullptr);
}

// E: MFConv1 (tmpNr -> embN f32 + embNb bf16) || EdgeConv1 GEMM (Em0 -> Bm,Cm)
__global__ __launch_bounds__(256) void kE(
    const u16* __restrict__ tmpNr, const u16* __restrict__ Wfrag,
    const float* __restrict__ b_lin, const int* __restrict__ rowptr,
    const int* __restrict__ src, const int* __restrict__ tbl_d,
    const int* __restrict__ tbl_base, const int* __restrict__ tbl_cnt,
    const int* __restrict__ nlist, float* __restrict__ embN, u16* __restrict__ embNb,
    const u16* __restrict__ Em0, const u16* __restrict__ Wefrag,
    u16* __restrict__ Bm, float* __restrict__ Cm) {
  __shared__ __align__(16) char sm[16384];
  __shared__ int nid[32];
  if (blockIdx.x < MAX_TBL)
    dev_MF_mfma<1>(blockIdx.x, tmpNr, Wfrag, b_lin, rowptr, src, tbl_d, tbl_base,
                   tbl_cnt, nlist, embN, embNb, sm, nid);
  else
    dev_EG_mfma<true, false>(blockIdx.x - MAX_TBL, nullptr, Em0, Wefrag, Bm, Cm, sm);
}

// F: EdgeConv1 aggregation (-> embE f32) + readout node gather (embNb -> h)
__global__ __launch_bounds__(256) void kF(
    const u16* __restrict__ Bm, const float* __restrict__ Cm,
    const float* __restrict__ b_edge, const int* __restrict__ deg,
    const int* __restrict__ rowptr, const int* __restrict__ src,
    const u16* __restrict__ embNb, float* __restrict__ embE, float* __restrict__ h) {
  dev_EA<false, true>(blockIdx.x, Bm, Cm, b_edge, deg, rowptr, src, embNb,
                      nullptr, embE, h);
}

// G: pool + mlp0 + mlp1 fused (one block per graph)
__global__ __launch_bounds__(256) void k_readout(
    const float* __restrict__ hf, const float* __restrict__ embE,
    const int* __restrict__ deg, const int* __restrict__ gstart,
    const float* __restrict__ W0, const float* __restrict__ b0,
    const float* __restrict__ W1, const float* __restrict__ b1,
    float* __restrict__ out0) {
  __shared__ float gs[256];
  __shared__ float hid[256];
  int g = blockIdx.x, j = threadIdx.x;
  int s = gstart[g], e = gstart[g + 1];
  float acc = 0.f;
  if (j < DIM) {
    for (int i = s; i < e; ++i) acc += hf[(size_t)i * DIM + j];
  } else {
    int jj = j - DIM;
    for (int i = s; i < e; ++i)
      acc += (float)deg[i] * fmaxf(embE[(size_t)i * DIM + jj], 0.f);
  }
  gs[j] = acc;
  __syncthreads();
  float a0 = b0[j];
  for (int k = 0; k < 256; ++k) a0 += gs[k] * W0[k * 256 + j];
  hid[j] = fmaxf(a0, 0.f);
  __syncthreads();
  if (j < OUT_DIM) {
    float a1 = b1[j];
    for (int k = 0; k < HIDDEN; ++k) a1 += hid[k] * W1[k * OUT_DIM + j];
    out0[g * OUT_DIM + j] = fmaxf(a1, 0.f);
  }
}

// ---------------- launch ----------------
extern "C" void kernel_launch(void* const* d_in, const int* in_sizes, int n_in,
                              void* d_out, int out_size, void* d_ws, size_t ws_size,
                              hipStream_t stream) {
  const float* x_in   = (const float*)d_in[0];
  const float* ea_in  = (const float*)d_in[1];
  const int*   ei     = (const int*)d_in[2];
  const int*   batch  = (const int*)d_in[3];
  const float* W_lin  = (const float*)d_in[4];
  const float* b_lin  = (const float*)d_in[5];
  const float* W_root = (const float*)d_in[6];
  const float* W_edge = (const float*)d_in[7];
  const float* b_edge = (const float*)d_in[8];
  const float* W0     = (const float*)d_in[9];
  const float* b0     = (const float*)d_in[10];
  const float* W1     = (const float*)d_in[11];
  const float* b1     = (const float*)d_in[12];
  const int* row = ei;
  const int* col = ei + N_EDGES;

  float* out0 = (float*)d_out;                  // [256,16]
  float* embN = out0 + N_GRAPHS * OUT_DIM;      // [50000,128] final pre-relu MFConv out
  float* embE = embN + (size_t)N_NODES * DIM;   // [600000,128] final pre-relu EdgeConv out

  char* wsp = (char*)d_ws;
  auto alloc = [&](size_t bytes) {
    char* p = wsp;
    wsp += (bytes + 255) & ~(size_t)255;
    return p;
  };
  int* deg      = (int*)alloc((size_t)N_NODES * 4);
  int* rowptr   = (int*)alloc((size_t)(N_NODES + 1) * 4);
  int* cursor   = (int*)alloc((size_t)N_NODES * 4);
  int* src      = (int*)alloc((size_t)N_EDGES * 4);
  int* nlist    = (int*)alloc((size_t)N_NODES * 4);
  int* bcur     = (int*)alloc(16 * 4);
  int* tbl_d    = (int*)alloc(MAX_TBL * 4);
  int* tbl_base = (int*)alloc(MAX_TBL * 4);
  int* tbl_cnt  = (int*)alloc(MAX_TBL * 4);
  int* gstart   = (int*)alloc(257 * 4);
  u16* xb       = (u16*)alloc((size_t)N_NODES * DIM * 2);   // bf16 x_in
  u16* tmpNr    = (u16*)alloc((size_t)N_NODES * DIM * 2);   // bf16 relu(MF0 out)
  u16* embNb    = (u16*)alloc((size_t)N_NODES * DIM * 2);   // bf16 relu(MF1 out)
  u16* Em0      = (u16*)alloc((size_t)N_NODES * DIM * 2);   // bf16 EA0 out
  u16* Bm       = (u16*)alloc((size_t)N_NODES * DIM * 2);   // bf16 EG out (gathered)
  float* Cm     = (float*)alloc((size_t)N_NODES * DIM * 4); // f32 EG out (streamed)
  float* h      = (float*)alloc((size_t)N_NODES * DIM * 4); // readout node gather
  u16* Wfrag    = (u16*)alloc((size_t)11 * 8 * 8 * 64 * 8 * 2);  // 720 KB
  u16* Wefrag   = (u16*)alloc((size_t)4 * 16 * 64 * 8 * 2);      // 64 KB

  hipMemsetAsync(deg, 0, (size_t)N_NODES * 4, stream);
  // emb_edge rows [50000, 600000) are exactly 0 (empty segment-max -> where -> 0)
  hipMemsetAsync(embE + (size_t)N_NODES * DIM, 0,
                 (size_t)(N_EDGES - N_NODES) * DIM * sizeof(float), stream);

  // 1: x->bf16 || weight fragment pre-swizzle || deg count
  kPrep<<<XCONV_B + WF_B + WEF_B + EB, 256, 0, stream>>>(
      x_in, xb, W_lin, W_root, Wfrag, W_edge, Wefrag, col, deg);
  // 2: CSR scan + buckets + graph bounds
  k_setup<<<1, 1024, 0, stream>>>(deg, batch, rowptr, cursor, bcur,
                                  tbl_d, tbl_base, tbl_cnt, gstart);
  // 3: edge scatter + node scatter || EdgeConv0 GEMM
  k_scatter_fused<<<NB + EB + GEMM_GRID, 256, 0, stream>>>(
      row, col, cursor, src, deg, bcur, nlist, ea_in, Wefrag, Bm, Cm);
  // 4: MFConv0 || EdgeConv0 aggregation
  kD<<<MAX_TBL + AGG_GRID, 256, 0, stream>>>(xb, Wfrag, b_lin, rowptr, src,
                                             tbl_d, tbl_base, tbl_cnt, nlist, tmpNr,
                                             Bm, Cm, b_edge, deg, Em0);
  // 5: MFConv1 || EdgeConv1 GEMM
  kE<<<MAX_TBL + GEMM_GRID, 256, 0, stream>>>(tmpNr, Wfrag, b_lin, rowptr, src,
                                              tbl_d, tbl_base, tbl_cnt, nlist,
                                              embN, embNb, Em0, Wefrag, Bm, Cm);
  // 6: EdgeConv1 aggregation + readout node gather (one CSR walk)
  kF<<<AGG_GRID, 256, 0, stream>>>(Bm, Cm, b_edge, deg, rowptr, src, embNb, embE, h);
  // 7: pool + MLP
  k_readout<<<N_GRAPHS, 256, 0, stream>>>(h, embE, deg, gstart, W0, b0, W1, b1, out0);
}

// Round 4
// 894.768 us; speedup vs baseline: 1.6112x; 1.0209x over previous
//
#include <hip/hip_runtime.h>
#include <cfloat>

#define N_NODES 50000
#define N_EDGES 600000
#define DIM 128
#define N_GRAPHS 256
#define HIDDEN 256
#define OUT_DIM 16
#define MAX_DEG 10
#define MAX_TBL 1600
#define GEMM_GRID 1563  // (N_NODES+31)/32
#define AGG_GRID 12500  // (N_NODES+3)/4
#define EB 2344         // (N_EDGES+255)/256
#define NB 196          // (N_NODES+255)/256
#define XCONV_B 6250    // 50000*128/4/256
#define WF_B 176        // 11*8*8*64/256
#define WEF_B 16        // 4*16*64/256
#define ZF_B 4096       // zero-fill blocks fused into kD
#define ZF_N4 17600000  // (N_EDGES-N_NODES)*DIM/4 float4s
#define PSUB 8          // pool sub-blocks per graph

typedef unsigned short u16;
typedef __attribute__((ext_vector_type(8))) short bf16x8;
typedef __attribute__((ext_vector_type(4))) float f32x4;

__device__ __forceinline__ float bf2f(u16 u) {
  union { unsigned u; float f; } c; c.u = ((unsigned)u) << 16; return c.f;
}
__device__ __forceinline__ u16 f2bf(float f) {
  union { float f; unsigned u; } c; c.f = f;
  return (u16)((c.u + 0x7FFFu + ((c.u >> 16) & 1u)) >> 16);
}
__device__ __forceinline__ float4 relu4(float4 v) {
  return make_float4(fmaxf(v.x, 0.f), fmaxf(v.y, 0.f), fmaxf(v.z, 0.f), fmaxf(v.w, 0.f));
}
__device__ __forceinline__ void fma4b(float4& a, float m, ushort4 v) {
  a.x = fmaf(m, bf2f(v.x), a.x); a.y = fmaf(m, bf2f(v.y), a.y);
  a.z = fmaf(m, bf2f(v.z), a.z); a.w = fmaf(m, bf2f(v.w), a.w);
}
__device__ __forceinline__ void max4b(float4& a, ushort4 v) {
  a.x = fmaxf(a.x, bf2f(v.x)); a.y = fmaxf(a.y, bf2f(v.y));
  a.z = fmaxf(a.z, bf2f(v.z)); a.w = fmaxf(a.w, bf2f(v.w));
}

// ---------------- prep: x->bf16, weight fragment pre-swizzle, deg count ----------------
__global__ __launch_bounds__(256) void kPrep(
    const float* __restrict__ x_in, u16* __restrict__ xb,
    const float* __restrict__ W_lin, const float* __restrict__ W_root,
    u16* __restrict__ Wfrag, const float* __restrict__ W_edge,
    u16* __restrict__ Wefrag, const int* __restrict__ col, int* __restrict__ deg) {
  int b = blockIdx.x, t = threadIdx.x;
  if (b < XCONV_B) {
    size_t i = ((size_t)b * 256 + t) * 4;
    float4 v = *(const float4*)(x_in + i);
    ushort4 o; o.x = f2bf(v.x); o.y = f2bf(v.y); o.z = f2bf(v.z); o.w = f2bf(v.w);
    *(ushort4*)(xb + i) = o;
  } else if (b < XCONV_B + WF_B) {
    int tid = (b - XCONV_B) * 256 + t;
    int lane = tid & 63, f = tid >> 6;        // f < 704 = 11*64
    int d = f >> 6, rem = f & 63, ks = rem >> 3, nt = rem & 7;
    u16* dst = Wfrag + ((size_t)f * 64 + lane) * 8;
    int n = nt * 16 + (lane & 15);
#pragma unroll
    for (int j = 0; j < 8; ++j) {
      int k = ks * 32 + (lane >> 4) * 8 + j;
      float v = (k < 128) ? W_lin[((size_t)d * 128 + k) * 128 + n]
                          : W_root[((size_t)d * 128 + (k - 128)) * 128 + n];
      dst[j] = f2bf(v);
    }
  } else if (b < XCONV_B + WF_B + WEF_B) {
    int tid = (b - XCONV_B - WF_B) * 256 + t;  // < 4096
    int lane = tid & 63, f = tid >> 6;         // f < 64
    int ks = f >> 4, nt = f & 15;
    u16* dst = Wefrag + ((size_t)f * 64 + lane) * 8;
    int n2 = nt * 16 + (lane & 15);
#pragma unroll
    for (int j = 0; j < 8; ++j) {
      int k = ks * 32 + (lane >> 4) * 8 + j;
      float v;
      if (n2 < 128) v = W_edge[(size_t)(128 + k) * 128 + n2];
      else { int n = n2 - 128; v = W_edge[(size_t)k * 128 + n] - W_edge[(size_t)(128 + k) * 128 + n]; }
      dst[j] = f2bf(v);
    }
  } else {
    int e = (b - XCONV_B - WF_B - WEF_B) * 256 + t;
    if (e < N_EDGES) atomicAdd(&deg[col[e]], 1);
  }
}

// ---------------- setup: scan + histogram + bucket table + graph bounds ----------------
__global__ void k_setup(const int* __restrict__ deg, const int* __restrict__ batch,
                        int* __restrict__ rowptr, int* __restrict__ cursor,
                        int* __restrict__ bcur, int* __restrict__ tbl_d,
                        int* __restrict__ tbl_base, int* __restrict__ tbl_cnt,
                        int* __restrict__ gstart) {
  __shared__ int tsum[1024];
  __shared__ int hist[MAX_DEG + 1];
  __shared__ int boff[MAX_DEG + 1];
  __shared__ int tblStart[MAX_DEG + 2];
  const int CH = (N_NODES + 1023) / 1024;  // 49
  int t = threadIdx.x;
  if (t <= MAX_DEG) hist[t] = 0;
  __syncthreads();
  for (int base2 = 0; base2 < N_NODES; base2 += 1024) {
    int i = base2 + t;
    int d = (i < N_NODES) ? min(deg[i], MAX_DEG) : -1;
#pragma unroll
    for (int dd = 0; dd <= MAX_DEG; ++dd) {
      unsigned long long m = __ballot(d == dd);
      if ((t & 63) == 0 && m) atomicAdd(&hist[dd], (int)__popcll(m));
    }
  }
  int lo = t * CH, hi = min(lo + CH, N_NODES);
  int s = 0;
  for (int i = lo; i < hi; ++i) s += deg[i];
  tsum[t] = s;
  __syncthreads();
  for (int off = 1; off < 1024; off <<= 1) {
    int v = (t >= off) ? tsum[t - off] : 0;
    __syncthreads();
    tsum[t] += v;
    __syncthreads();
  }
  int pre = (t == 0) ? 0 : tsum[t - 1];
  for (int i = lo; i < hi; ++i) { rowptr[i] = pre; cursor[i] = pre; pre += deg[i]; }
  if (t == 1023) rowptr[N_NODES] = tsum[1023];
  if (t == 0) {
    int off = 0, nb = 0;
    for (int d = 0; d <= MAX_DEG; ++d) {
      boff[d] = off; bcur[d] = off; off += hist[d];
      tblStart[d] = nb; nb += (hist[d] + 31) / 32;
    }
    tblStart[MAX_DEG + 1] = nb;
  }
  __syncthreads();
  int totalb = tblStart[MAX_DEG + 1];
  for (int d = 0; d <= MAX_DEG; ++d) {
    int nblk = (hist[d] + 31) / 32;
    int st = tblStart[d];
    for (int idx = t; idx < nblk; idx += 1024) {
      tbl_d[st + idx] = d;
      tbl_base[st + idx] = boff[d] + idx * 32;
      tbl_cnt[st + idx] = min(32, hist[d] - idx * 32);
    }
  }
  for (int idx = totalb + t; idx < MAX_TBL; idx += 1024) tbl_d[idx] = -1;
  for (int g = t; g <= N_GRAPHS; g += 1024) {
    int lo2 = 0, hi2 = N_NODES;
    while (lo2 < hi2) {
      int mid = (lo2 + hi2) >> 1;
      if (batch[mid] < g) lo2 = mid + 1; else hi2 = mid;
    }
    gstart[g] = lo2;
  }
}

// ---------------- EdgeConv GEMM via MFMA (device body) ----------------
// out[32 x 256] = e[32 x 128] @ [W_bot | W_diff]; n2<128 -> Bm (bf16), else Cm (f32)
template <bool F32IN>
__device__ __forceinline__ void dev_EG_mfma(
    int bid, const float* __restrict__ ef, const u16* __restrict__ eb,
    const u16* __restrict__ Wefrag, u16* __restrict__ Bm, float* __restrict__ Cm,
    char* Es /*32*256B swizzled*/) {
  int base = bid * 32;
  int cnt = min(32, N_NODES - base);
  int tid = threadIdx.x;
  if (F32IN) {
    int i0 = tid >> 5, c4 = (tid & 31) * 4;
#pragma unroll
    for (int it = 0; it < 4; ++it) {
      int i = i0 + it * 8;
      int r = base + min(i, cnt - 1);
      float4 v = *(const float4*)(ef + (size_t)r * DIM + c4);
      ushort4 o; o.x = f2bf(v.x); o.y = f2bf(v.y); o.z = f2bf(v.z); o.w = f2bf(v.w);
      unsigned by = (unsigned)(i * 256 + c4 * 2) ^ (unsigned)((i & 7) << 4);
      *(ushort4*)(Es + by) = o;
    }
  } else {
    // input is post-relu bf16 (Em0 stored relu'd) -> plain copy
    int i0 = tid >> 4, c8 = (tid & 15) * 8;
#pragma unroll
    for (int it = 0; it < 2; ++it) {
      int i = i0 + it * 16;
      int r = base + min(i, cnt - 1);
      ushort4 v0 = *(const ushort4*)(eb + (size_t)r * DIM + c8);
      ushort4 v1 = *(const ushort4*)(eb + (size_t)r * DIM + c8 + 4);
      unsigned by = (unsigned)(i * 256 + c8 * 2) ^ (unsigned)((i & 7) << 4);
      *(ushort4*)(Es + by) = v0;
      *(ushort4*)(Es + by + 8) = v1;
    }
  }
  __syncthreads();
  int w = tid >> 6, l = tid & 63, mtile = w & 1, g = w >> 1;
  int l4 = l >> 4, l16 = l & 15;
  f32x4 acc[8];
#pragma unroll
  for (int nt = 0; nt < 8; ++nt) acc[nt] = (f32x4){0.f, 0.f, 0.f, 0.f};
  for (int ks = 0; ks < 4; ++ks) {
    unsigned by = (unsigned)((mtile * 16 + l16) * 256 + ks * 64 + l4 * 16) ^
                  (unsigned)((l16 & 7) << 4);
    bf16x8 af = *(const bf16x8*)(Es + by);
#pragma unroll
    for (int nt = 0; nt < 8; ++nt) {
      int ntile = g * 8 + nt;
      bf16x8 bf = *(const bf16x8*)(Wefrag + (((size_t)ks * 16 + ntile) * 64 + l) * 8);
      acc[nt] = __builtin_amdgcn_mfma_f32_16x16x32_bf16(af, bf, acc[nt], 0, 0, 0);
    }
  }
#pragma unroll
  for (int nt = 0; nt < 8; ++nt) {
    int n2 = (g * 8 + nt) * 16 + l16;
#pragma unroll
    for (int r = 0; r < 4; ++r) {
      int rowi = mtile * 16 + l4 * 4 + r;
      if (rowi < cnt) {
        size_t node = base + rowi;
        if (n2 < 128) Bm[node * DIM + n2] = f2bf(acc[nt][r]);
        else Cm[node * DIM + (n2 - 128)] = acc[nt][r];
      }
    }
  }
}

// ---------------- fused scatter + EG0 ----------------
__global__ __launch_bounds__(256) void k_scatter_fused(
    const int* __restrict__ row, const int* __restrict__ col,
    int* __restrict__ cursor, int* __restrict__ src,
    const int* __restrict__ deg, int* __restrict__ bcur, int* __restrict__ nlist,
    const float* __restrict__ ea, const u16* __restrict__ Wefrag,
    u16* __restrict__ Bm, float* __restrict__ Cm) {
  __shared__ __align__(16) char sm[8192];
  __shared__ int lh[MAX_DEG + 1];
  __shared__ int gbase[MAX_DEG + 1];
  int b = blockIdx.x;
  if (b < NB) {
    int t = threadIdx.x;
    if (t <= MAX_DEG) lh[t] = 0;
    __syncthreads();
    int i = b * 256 + t;
    int bk = 0, r = 0;
    if (i < N_NODES) { bk = min(deg[i], MAX_DEG); r = atomicAdd(&lh[bk], 1); }
    __syncthreads();
    if (t <= MAX_DEG) gbase[t] = lh[t] ? atomicAdd(&bcur[t], lh[t]) : 0;
    __syncthreads();
    if (i < N_NODES) nlist[gbase[bk] + r] = i;
  } else if (b < NB + EB) {
    int e = (b - NB) * 256 + threadIdx.x;
    if (e < N_EDGES) {
      int p = atomicAdd(&cursor[col[e]], 1);
      src[p] = row[e];
    }
  } else {
    dev_EG_mfma<true>(b - NB - EB, ea, nullptr, Wefrag, Bm, Cm, sm);
  }
}

// ---------------- MFConv via MFMA, optionally fused with EdgeConv aggregation ----------------
// A[32 x 256] = [h | x] (bf16, swizzled LDS), B = Wfrag[d], C-tile 32x128
// MODE 0: store bf16 relu -> outb only.  MODE 1: f32 raw -> outf AND bf16 relu -> outb.
// FUSE_EA: same CSR walk also max-gathers Bm rows -> Em0 = relu(Cm + b_edge + max)
template <int MODE, bool FUSE_EA>
__device__ __forceinline__ void dev_MF_mfma(
    int b, const u16* __restrict__ xb, const u16* __restrict__ Wfrag,
    const float* __restrict__ b_lin, const int* __restrict__ rowptr,
    const int* __restrict__ src, const int* __restrict__ tbl_d,
    const int* __restrict__ tbl_base, const int* __restrict__ tbl_cnt,
    const int* __restrict__ nlist, float* __restrict__ outf, u16* __restrict__ outb,
    const u16* __restrict__ Bm, const float* __restrict__ Cm,
    const float* __restrict__ b_edge, u16* __restrict__ Em0,
    char* As /*32*512B swizzled*/, int* nid) {
  int d = tbl_d[b];
  if (d < 0) return;
  int base = tbl_base[b], cnt = tbl_cnt[b];
  int tid = threadIdx.x;
  if (tid < 32) nid[tid] = nlist[base + min(tid, cnt - 1)];
  __syncthreads();
  int q = tid >> 5, lr = tid & 31;
  for (int i = q; i < 32; i += 8) {
    if (i < cnt) {
      int node = nid[i];
      int s = rowptr[node], e = rowptr[node + 1], e1 = e - 1;
      float4 a = make_float4(0.f, 0.f, 0.f, 0.f);
      float4 m = make_float4(-FLT_MAX, -FLT_MAX, -FLT_MAX, -FLT_MAX);
      for (int p = s; p < e; p += 8) {
        int idx[8]; float msk[8];
#pragma unroll
        for (int u = 0; u < 8; ++u) {
          int pe = p + u;
          idx[u] = src[min(pe, e1)];
          msk[u] = (pe < e) ? 1.f : 0.f;
        }
#pragma unroll
        for (int u = 0; u < 8; ++u) {
          fma4b(a, msk[u], *(const ushort4*)(xb + (size_t)idx[u] * DIM + 4 * lr));
          if (FUSE_EA)  // dup-clamp safe for max
            max4b(m, *(const ushort4*)(Bm + (size_t)idx[u] * DIM + 4 * lr));
        }
      }
      ushort4 xv = *(const ushort4*)(xb + (size_t)node * DIM + 4 * lr);
      ushort4 hb; hb.x = f2bf(a.x); hb.y = f2bf(a.y); hb.z = f2bf(a.z); hb.w = f2bf(a.w);
      unsigned swz = (unsigned)((i & 7) << 4);
      *(ushort4*)(As + (((unsigned)(i * 512 + 8 * lr)) ^ swz)) = hb;
      *(ushort4*)(As + (((unsigned)(i * 512 + 256 + 8 * lr)) ^ swz)) = xv;
      if (FUSE_EA) {
        ushort4 ob;
        if (s == e) { ob.x = ob.y = ob.z = ob.w = 0; }
        else {
          const float4 c = ((const float4*)(Cm + (size_t)node * DIM))[lr];
          const float4 be = ((const float4*)b_edge)[lr];
          ob.x = f2bf(fmaxf(c.x + be.x + m.x, 0.f));
          ob.y = f2bf(fmaxf(c.y + be.y + m.y, 0.f));
          ob.z = f2bf(fmaxf(c.z + be.z + m.z, 0.f));
          ob.w = f2bf(fmaxf(c.w + be.w + m.w, 0.f));
        }
        *(ushort4*)(Em0 + (size_t)node * DIM + 4 * lr) = ob;
      }
    }
  }
  __syncthreads();
  int w = tid >> 6, l = tid & 63, mtile = w & 1, g = w >> 1;
  int l4 = l >> 4, l16 = l & 15;
  f32x4 acc[4];
#pragma unroll
  for (int nt = 0; nt < 4; ++nt) {
    float bv = b_lin[d * DIM + (g * 4 + nt) * 16 + l16];
    acc[nt] = (f32x4){bv, bv, bv, bv};
  }
  const u16* Wf = Wfrag + (size_t)d * 32768;  // 8ks*8nt*64*8
  for (int ks = 0; ks < 8; ++ks) {
    unsigned by = (unsigned)((mtile * 16 + l16) * 512 + ks * 64 + l4 * 16) ^
                  (unsigned)((l16 & 7) << 4);
    bf16x8 af = *(const bf16x8*)(As + by);
#pragma unroll
    for (int nt = 0; nt < 4; ++nt) {
      int ntile = g * 4 + nt;
      bf16x8 bf = *(const bf16x8*)(Wf + (((size_t)ks * 8 + ntile) * 64 + l) * 8);
      acc[nt] = __builtin_amdgcn_mfma_f32_16x16x32_bf16(af, bf, acc[nt], 0, 0, 0);
    }
  }
#pragma unroll
  for (int nt = 0; nt < 4; ++nt) {
    int n = (g * 4 + nt) * 16 + l16;
#pragma unroll
    for (int r = 0; r < 4; ++r) {
      int rowi = mtile * 16 + l4 * 4 + r;
      if (rowi < cnt) {
        float v = acc[nt][r];
        size_t o = (size_t)nid[rowi] * DIM + n;
        if (MODE == 1) { outf[o] = v; outb[o] = f2bf(fmaxf(v, 0.f)); }
        else outb[o] = f2bf(fmaxf(v, 0.f));
      }
    }
  }
}

// ---------------- EdgeConv1 aggregation + readout node gather (one CSR walk) ----------------
__global__ __launch_bounds__(256) void kF(
    const u16* __restrict__ Bm, const float* __restrict__ Cm,
    const float* __restrict__ b_edge, const int* __restrict__ deg,
    const int* __restrict__ rowptr, const int* __restrict__ src,
    const u16* __restrict__ embNb, float* __restrict__ embE, float* __restrict__ h) {
  int w = threadIdx.x >> 6;
  int node = blockIdx.x * 4 + w;
  if (node >= N_NODES) return;
  int l = threadIdx.x & 63, half = l >> 5, lr = l & 31;
  if (deg[node] == 0) {
    if (half == 0) {
      ((float4*)(embE + (size_t)node * DIM))[lr] = make_float4(0.f, 0.f, 0.f, 0.f);
      ((float4*)(h + (size_t)node * DIM))[lr] = make_float4(0.f, 0.f, 0.f, 0.f);
    }
    return;
  }
  int s = rowptr[node], e = rowptr[node + 1], e1 = e - 1;
  float4 m = make_float4(-FLT_MAX, -FLT_MAX, -FLT_MAX, -FLT_MAX);
  float4 a = make_float4(0.f, 0.f, 0.f, 0.f);
  for (int p = s; p < e; p += 8) {
    int idx[4]; float msk[4];
#pragma unroll
    for (int u = 0; u < 4; ++u) {
      int pe = p + 2 * u + half;
      idx[u] = src[min(pe, e1)];
      msk[u] = (pe < e) ? 1.f : 0.f;
    }
#pragma unroll
    for (int u = 0; u < 4; ++u) {
      max4b(m, *(const ushort4*)(Bm + (size_t)idx[u] * DIM + 4 * lr));  // dup-clamp safe
      fma4b(a, msk[u], *(const ushort4*)(embNb + (size_t)idx[u] * DIM + 4 * lr));
    }
  }
  m.x = fmaxf(m.x, __shfl_xor(m.x, 32));
  m.y = fmaxf(m.y, __shfl_xor(m.y, 32));
  m.z = fmaxf(m.z, __shfl_xor(m.z, 32));
  m.w = fmaxf(m.w, __shfl_xor(m.w, 32));
  a.x += __shfl_xor(a.x, 32); a.y += __shfl_xor(a.y, 32);
  a.z += __shfl_xor(a.z, 32); a.w += __shfl_xor(a.w, 32);
  if (half == 0) {
    const float4 c = ((const float4*)(Cm + (size_t)node * DIM))[lr];
    const float4 be = ((const float4*)b_edge)[lr];
    ((float4*)(embE + (size_t)node * DIM))[lr] =
        make_float4(c.x + be.x + m.x, c.y + be.y + m.y, c.z + be.z + m.z, c.w + be.w + m.w);
    ((float4*)(h + (size_t)node * DIM))[lr] = a;
  }
}

// ---------------- fused dispatches ----------------
// D: MFConv0 + EdgeConv0 aggregation (one walk)  ||  embE tail zero-fill
__global__ __launch_bounds__(256) void kD(
    const u16* __restrict__ xb, const u16* __restrict__ Wfrag,
    const float* __restrict__ b_lin, const int* __restrict__ rowptr,
    const int* __restrict__ src, const int* __restrict__ tbl_d,
    const int* __restrict__ tbl_base, const int* __restrict__ tbl_cnt,
    const int* __restrict__ nlist, u16* __restrict__ tmpNr,
    const u16* __restrict__ Bm, const float* __restrict__ Cm,
    const float* __restrict__ b_edge, u16* __restrict__ Em0,
    float* __restrict__ ztail) {
  __shared__ __align__(16) char sm[16384];
  __shared__ int nid[32];
  if (blockIdx.x < MAX_TBL) {
    dev_MF_mfma<0, true>(blockIdx.x, xb, Wfrag, b_lin, rowptr, src, tbl_d, tbl_base,
                         tbl_cnt, nlist, nullptr, tmpNr, Bm, Cm, b_edge, Em0, sm, nid);
  } else {
    size_t gid = (size_t)(blockIdx.x - MAX_TBL) * 256 + threadIdx.x;
    float4 z = make_float4(0.f, 0.f, 0.f, 0.f);
    for (size_t i = gid; i < ZF_N4; i += (size_t)ZF_B * 256)
      ((float4*)ztail)[i] = z;
  }
}

// E: MFConv1 (tmpNr -> embN f32 + embNb bf16) || EdgeConv1 GEMM (Em0 -> Bm,Cm)
__global__ __launch_bounds__(256) void kE(
    const u16* __restrict__ tmpNr, const u16* __restrict__ Wfrag,
    const float* __restrict__ b_lin, const int* __restrict__ rowptr,
    const int* __restrict__ src, const int* __restrict__ tbl_d,
    const int* __restrict__ tbl_base, const int* __restrict__ tbl_cnt,
    const int* __restrict__ nlist, float* __restrict__ embN, u16* __restrict__ embNb,
    const u16* __restrict__ Em0, const u16* __restrict__ Wefrag,
    u16* __restrict__ Bm, float* __restrict__ Cm) {
  __shared__ __align__(16) char sm[16384];
  __shared__ int nid[32];
  if (blockIdx.x < MAX_TBL)
    dev_MF_mfma<1, false>(blockIdx.x, tmpNr, Wfrag, b_lin, rowptr, src, tbl_d, tbl_base,
                          tbl_cnt, nlist, embN, embNb, nullptr, nullptr, nullptr, nullptr,
                          sm, nid);
  else
    dev_EG_mfma<false>(blockIdx.x - MAX_TBL, nullptr, Em0, Wefrag, Bm, Cm, sm);
}

// ---------------- Readout: pool partials (8 sub-blocks/graph) + MLP ----------------
__global__ __launch_bounds__(256) void kPool(
    const float* __restrict__ hf, const float* __restrict__ embE,
    const int* __restrict__ deg, const int* __restrict__ gstart,
    float* __restrict__ gfp) {
  int g = blockIdx.x >> 3, sub = blockIdx.x & (PSUB - 1);
  int j = threadIdx.x;
  int s = gstart[g], e = gstart[g + 1];
  int ch = (e - s + PSUB - 1) / PSUB;
  int lo = s + sub * ch, hi = min(lo + ch, e);
  float acc = 0.f;
  if (j < DIM) {
    for (int i = lo; i < hi; ++i) acc += hf[(size_t)i * DIM + j];
  } else {
    int jj = j - DIM;
    for (int i = lo; i < hi; ++i)
      acc += (float)deg[i] * fmaxf(embE[(size_t)i * DIM + jj], 0.f);
  }
  gfp[(size_t)blockIdx.x * 256 + j] = acc;
}

__global__ __launch_bounds__(256) void kMLP(
    const float* __restrict__ gfp, const float* __restrict__ W0,
    const float* __restrict__ b0, const float* __restrict__ W1,
    const float* __restrict__ b1, float* __restrict__ out0) {
  __shared__ float gs[256];
  __shared__ float hid[256];
  int g = blockIdx.x, j = threadIdx.x;
  float acc = 0.f;
#pragma unroll
  for (int sub = 0; sub < PSUB; ++sub)
    acc += gfp[((size_t)g * PSUB + sub) * 256 + j];
  gs[j] = acc;
  __syncthreads();
  float a0 = b0[j];
  for (int k = 0; k < 256; ++k) a0 += gs[k] * W0[k * 256 + j];
  hid[j] = fmaxf(a0, 0.f);
  __syncthreads();
  if (j < OUT_DIM) {
    float a1 = b1[j];
    for (int k = 0; k < HIDDEN; ++k) a1 += hid[k] * W1[k * OUT_DIM + j];
    out0[g * OUT_DIM + j] = fmaxf(a1, 0.f);
  }
}

// ---------------- launch ----------------
extern "C" void kernel_launch(void* const* d_in, const int* in_sizes, int n_in,
                              void* d_out, int out_size, void* d_ws, size_t ws_size,
                              hipStream_t stream) {
  const float* x_in   = (const float*)d_in[0];
  const float* ea_in  = (const float*)d_in[1];
  const int*   ei     = (const int*)d_in[2];
  const int*   batch  = (const int*)d_in[3];
  const float* W_lin  = (const float*)d_in[4];
  const float* b_lin  = (const float*)d_in[5];
  const float* W_root = (const float*)d_in[6];
  const float* W_edge = (const float*)d_in[7];
  const float* b_edge = (const float*)d_in[8];
  const float* W0     = (const float*)d_in[9];
  const float* b0     = (const float*)d_in[10];
  const float* W1     = (const float*)d_in[11];
  const float* b1     = (const float*)d_in[12];
  const int* row = ei;
  const int* col = ei + N_EDGES;

  float* out0 = (float*)d_out;                  // [256,16]
  float* embN = out0 + N_GRAPHS * OUT_DIM;      // [50000,128] final pre-relu MFConv out
  float* embE = embN + (size_t)N_NODES * DIM;   // [600000,128] final pre-relu EdgeConv out

  char* wsp = (char*)d_ws;
  auto alloc = [&](size_t bytes) {
    char* p = wsp;
    wsp += (bytes + 255) & ~(size_t)255;
    return p;
  };
  int* deg      = (int*)alloc((size_t)N_NODES * 4);
  int* rowptr   = (int*)alloc((size_t)(N_NODES + 1) * 4);
  int* cursor   = (int*)alloc((size_t)N_NODES * 4);
  int* src      = (int*)alloc((size_t)N_EDGES * 4);
  int* nlist    = (int*)alloc((size_t)N_NODES * 4);
  int* bcur     = (int*)alloc(16 * 4);
  int* tbl_d    = (int*)alloc(MAX_TBL * 4);
  int* tbl_base = (int*)alloc(MAX_TBL * 4);
  int* tbl_cnt  = (int*)alloc(MAX_TBL * 4);
  int* gstart   = (int*)alloc(257 * 4);
  u16* xb       = (u16*)alloc((size_t)N_NODES * DIM * 2);   // bf16 x_in
  u16* tmpNr    = (u16*)alloc((size_t)N_NODES * DIM * 2);   // bf16 relu(MF0 out)
  u16* embNb    = (u16*)alloc((size_t)N_NODES * DIM * 2);   // bf16 relu(MF1 out)
  u16* Em0      = (u16*)alloc((size_t)N_NODES * DIM * 2);   // bf16 relu(EA0 out)
  u16* Bm       = (u16*)alloc((size_t)N_NODES * DIM * 2);   // bf16 EG out (gathered)
  float* Cm     = (float*)alloc((size_t)N_NODES * DIM * 4); // f32 EG out (streamed)
  float* h      = (float*)alloc((size_t)N_NODES * DIM * 4); // readout node gather
  float* gfp    = (float*)alloc((size_t)N_GRAPHS * PSUB * 256 * 4);  // pool partials
  u16* Wfrag    = (u16*)alloc((size_t)11 * 8 * 8 * 64 * 8 * 2);  // 720 KB
  u16* Wefrag   = (u16*)alloc((size_t)4 * 16 * 64 * 8 * 2);      // 64 KB

  hipMemsetAsync(deg, 0, (size_t)N_NODES * 4, stream);

  // 1: x->bf16 || weight fragment pre-swizzle || deg count
  kPrep<<<XCONV_B + WF_B + WEF_B + EB, 256, 0, stream>>>(
      x_in, xb, W_lin, W_root, Wfrag, W_edge, Wefrag, col, deg);
  // 2: CSR scan + buckets + graph bounds
  k_setup<<<1, 1024, 0, stream>>>(deg, batch, rowptr, cursor, bcur,
                                  tbl_d, tbl_base, tbl_cnt, gstart);
  // 3: edge scatter + node scatter || EdgeConv0 GEMM
  k_scatter_fused<<<NB + EB + GEMM_GRID, 256, 0, stream>>>(
      row, col, cursor, src, deg, bcur, nlist, ea_in, Wefrag, Bm, Cm);
  // 4: MFConv0 + EdgeConv0 aggregation (single CSR walk) || embE tail zero-fill
  kD<<<MAX_TBL + ZF_B, 256, 0, stream>>>(xb, Wfrag, b_lin, rowptr, src,
                                         tbl_d, tbl_base, tbl_cnt, nlist, tmpNr,
                                         Bm, Cm, b_edge, Em0,
                                         embE + (size_t)N_NODES * DIM);
  // 5: MFConv1 || EdgeConv1 GEMM
  kE<<<MAX_TBL + GEMM_GRID, 256, 0, stream>>>(tmpNr, Wfrag, b_lin, rowptr, src,
                                              tbl_d, tbl_base, tbl_cnt, nlist,
                                              embN, embNb, Em0, Wefrag, Bm, Cm);
  // 6: EdgeConv1 aggregation + readout node gather (one CSR walk)
  kF<<<AGG_GRID, 256, 0, stream>>>(Bm, Cm, b_edge, deg, rowptr, src, embNb, embE, h);
  // 7: pool partials, 8: MLP
  kPool<<<N_GRAPHS * PSUB, 256, 0, stream>>>(h, embE, deg, gstart, gfp);
  kMLP<<<N_GRAPHS, 256, 0, stream>>>(gfp, W0, b0, W1, b1, out0);
}